// Round 1
// baseline (634.662 us; speedup 1.0000x reference)
//
#include <hip/hip_runtime.h>

// ---------------------------------------------------------------------------
// VariationalGCNEncoder on MI355X
//   deg/CSR build (int atomics) -> dinv
//   h   = x @ W1                         (SGEMM, f32)
//   h1  = relu(A_norm @ h + b1)          (gather, bias+relu fused)
//   g   = A_norm @ h1                    (gather)    [shared by mu & logstd]
//   mu  = g @ W_mu + b_mu ; ls = g @ W_ls + b_ls     (SGEMM, split epilogue)
// ---------------------------------------------------------------------------

__global__ void count_deg(const int* __restrict__ dst, int E, int* __restrict__ degi) {
    int i = blockIdx.x * blockDim.x + threadIdx.x;
    if (i < E) atomicAdd(&degi[dst[i]], 1);
}

// 256 threads, 1024 elements per block. Writes chunk-local inclusive scan into
// row_ptr[ix+1], block totals into partials[].
__global__ __launch_bounds__(256) void scan_blocks(const int* __restrict__ degi, int n,
                                                   int* __restrict__ row_ptr,
                                                   int* __restrict__ partials) {
    __shared__ int sh[256];
    int t = threadIdx.x;
    int base = blockIdx.x * 1024;
    int idx0 = base + t * 4;
    int v[4];
#pragma unroll
    for (int i = 0; i < 4; ++i) {
        int ix = idx0 + i;
        v[i] = (ix < n) ? degi[ix] : 0;
    }
    int s = v[0] + v[1] + v[2] + v[3];
    sh[t] = s;
    __syncthreads();
    for (int off = 1; off < 256; off <<= 1) {
        int x = (t >= off) ? sh[t - off] : 0;
        __syncthreads();
        sh[t] += x;
        __syncthreads();
    }
    int run = sh[t] - s;  // exclusive prefix of this thread inside block
#pragma unroll
    for (int i = 0; i < 4; ++i) {
        int ix = idx0 + i;
        run += v[i];
        if (ix < n) row_ptr[ix + 1] = run;
    }
    if (t == 255) partials[blockIdx.x] = sh[255];
}

// nb <= 128. Exclusive scan of block totals, in place.
__global__ void scan_partials(int* __restrict__ partials, int nb) {
    __shared__ int sh[128];
    int t = threadIdx.x;
    int v = (t < nb) ? partials[t] : 0;
    sh[t] = v;
    __syncthreads();
    for (int off = 1; off < 128; off <<= 1) {
        int x = (t >= off) ? sh[t - off] : 0;
        __syncthreads();
        sh[t] += x;
        __syncthreads();
    }
    if (t < nb) partials[t] = sh[t] - v;
}

__global__ void finalize_rows(const int* __restrict__ degi, int n,
                              int* __restrict__ row_ptr, const int* __restrict__ partials,
                              int* __restrict__ cursor, float* __restrict__ dinv) {
    int i = blockIdx.x * blockDim.x + threadIdx.x;
    if (i == 0) row_ptr[0] = 0;
    if (i < n) {
        int p = partials[i >> 10];
        int rp1 = row_ptr[i + 1] + p;
        row_ptr[i + 1] = rp1;
        cursor[i] = rp1 - degi[i];                 // == final row_ptr[i]
        dinv[i] = rsqrtf((float)(degi[i] + 1));    // +1: self-loop
    }
}

__global__ void fill_csr(const int* __restrict__ src, const int* __restrict__ dst, int E,
                         int* __restrict__ cursor, int* __restrict__ csr_src) {
    int i = blockIdx.x * blockDim.x + threadIdx.x;
    if (i < E) {
        int p = atomicAdd(&cursor[dst[i]], 1);
        csr_src[p] = src[i];
    }
}

// One wave per destination node; lane l holds channels 2l, 2l+1.
// FUSE=1: out = relu(acc + bias). Self-loop folded into the init.
template <int FUSE>
__global__ __launch_bounds__(256) void gather_rows(const float* __restrict__ h,
                                                   const float* __restrict__ dinv,
                                                   const int* __restrict__ row_ptr,
                                                   const int* __restrict__ csr_src,
                                                   const float* __restrict__ bias,
                                                   float* __restrict__ out, int n) {
    int wid = (blockIdx.x * 256 + threadIdx.x) >> 6;
    int lane = threadIdx.x & 63;
    if (wid >= n) return;
    float dv = dinv[wid];
    int beg = row_ptr[wid];
    int end = row_ptr[wid + 1];
    float2 a = ((const float2*)(h + (size_t)wid * 128))[lane];
    float sw = dv * dv;  // self-loop norm
    float accx = a.x * sw, accy = a.y * sw;
    for (int j = beg; j < end; ++j) {
        int s = csr_src[j];
        float w = dv * dinv[s];
        float2 b = ((const float2*)(h + (size_t)s * 128))[lane];
        accx = fmaf(w, b.x, accx);
        accy = fmaf(w, b.y, accy);
    }
    if (FUSE) {
        float2 bb = ((const float2*)bias)[lane];
        accx = fmaxf(accx + bb.x, 0.0f);
        accy = fmaxf(accy + bb.y, 0.0f);
    }
    ((float2*)(out + (size_t)wid * 128))[lane] = make_float2(accx, accy);
}

// C[M,128] = A[M,128] @ B[128,128]; 256 thr, BM=BN=128, BK=32, 8x8 micro-tile
// split as rows {ty*4+i, 64+ty*4+i} x cols {tx*4+j, 64+tx*4+j}.
// MODE 0: B = B0 (128 wide), plain write to C0[M,128].
// MODE 1: B cols 0-63 from B0(=W_mu), 64-127 from B1(=W_ls); epilogue adds
//         bias and writes halves to C0 (mu) and C1 (logstd), each [M,64].
template <int MODE>
__global__ __launch_bounds__(256) void sgemm128(const float* __restrict__ A, int M,
                                                const float* __restrict__ B0,
                                                const float* __restrict__ B1,
                                                const float* __restrict__ bias0,
                                                const float* __restrict__ bias1,
                                                float* __restrict__ C0,
                                                float* __restrict__ C1) {
    __shared__ float As[32][132];
    __shared__ float Bs[32][128];
    int tid = threadIdx.x;
    int row0 = blockIdx.x * 128;
    int tx = tid & 15, ty = tid >> 4;
    float acc[8][8] = {};
    for (int k0 = 0; k0 < 128; k0 += 32) {
#pragma unroll
        for (int i = 0; i < 4; ++i) {
            int idx = tid + i * 256;       // 0..1023
            int r = idx >> 3;              // 0..127
            int c4 = (idx & 7) << 2;       // 0..28
            int grow = row0 + r;
            float4 v = make_float4(0.f, 0.f, 0.f, 0.f);
            if (grow < M) v = *(const float4*)(A + (size_t)grow * 128 + k0 + c4);
            As[c4 + 0][r] = v.x;
            As[c4 + 1][r] = v.y;
            As[c4 + 2][r] = v.z;
            As[c4 + 3][r] = v.w;
        }
#pragma unroll
        for (int i = 0; i < 4; ++i) {
            int idx = tid + i * 256;
            int r = idx >> 5;              // 0..31
            int c4 = (idx & 31) << 2;      // 0..124
            const float* bp;
            if (MODE == 0) {
                bp = B0 + (size_t)(k0 + r) * 128 + c4;
            } else {
                bp = (c4 < 64) ? (B0 + (size_t)(k0 + r) * 64 + c4)
                               : (B1 + (size_t)(k0 + r) * 64 + (c4 - 64));
            }
            *(float4*)&Bs[r][c4] = *(const float4*)bp;
        }
        __syncthreads();
#pragma unroll
        for (int k = 0; k < 32; ++k) {
            float a[8], b[8];
            *(float4*)&a[0] = *(const float4*)&As[k][ty * 4];
            *(float4*)&a[4] = *(const float4*)&As[k][64 + ty * 4];
            *(float4*)&b[0] = *(const float4*)&Bs[k][tx * 4];
            *(float4*)&b[4] = *(const float4*)&Bs[k][64 + tx * 4];
#pragma unroll
            for (int i = 0; i < 8; ++i)
#pragma unroll
                for (int j = 0; j < 8; ++j) acc[i][j] = fmaf(a[i], b[j], acc[i][j]);
        }
        __syncthreads();
    }
#pragma unroll
    for (int ig = 0; ig < 2; ++ig) {
#pragma unroll
        for (int ii = 0; ii < 4; ++ii) {
            int i = ig * 4 + ii;
            int grow = row0 + ig * 64 + ty * 4 + ii;
            if (grow >= M) continue;
#pragma unroll
            for (int jg = 0; jg < 2; ++jg) {
                float4 v = make_float4(acc[i][jg * 4 + 0], acc[i][jg * 4 + 1],
                                       acc[i][jg * 4 + 2], acc[i][jg * 4 + 3]);
                if (MODE == 0) {
                    *(float4*)(C0 + (size_t)grow * 128 + jg * 64 + tx * 4) = v;
                } else {
                    int c = tx * 4;
                    const float* bs = (jg == 0) ? bias0 : bias1;
                    v.x += bs[c + 0];
                    v.y += bs[c + 1];
                    v.z += bs[c + 2];
                    v.w += bs[c + 3];
                    float* cp = ((jg == 0) ? C0 : C1) + (size_t)grow * 64 + c;
                    *(float4*)cp = v;
                }
            }
        }
    }
}

extern "C" void kernel_launch(void* const* d_in, const int* in_sizes, int n_in,
                              void* d_out, int out_size, void* d_ws, size_t ws_size,
                              hipStream_t stream) {
    const float* x   = (const float*)d_in[0];
    const int*  eidx = (const int*)d_in[1];
    const float* W1  = (const float*)d_in[2];
    const float* b1  = (const float*)d_in[3];
    const float* Wmu = (const float*)d_in[4];
    const float* bmu = (const float*)d_in[5];
    const float* Wls = (const float*)d_in[6];
    const float* bls = (const float*)d_in[7];
    float* out = (float*)d_out;

    const int N = in_sizes[0] / 128;  // 100000
    const int E = in_sizes[1] / 2;    // 1600000
    const int* src = eidx;
    const int* dst = eidx + E;

    char* w = (char*)d_ws;
    size_t off = 0;
    auto alloc = [&](size_t bytes) {
        void* p = w + off;
        off += (bytes + 255) & ~(size_t)255;
        return p;
    };
    int*   degi     = (int*)alloc((size_t)N * 4);
    int*   row_ptr  = (int*)alloc((size_t)(N + 1) * 4);
    int*   cursor   = (int*)alloc((size_t)N * 4);
    float* dinv     = (float*)alloc((size_t)N * 4);
    int*   partials = (int*)alloc(512);
    int*   csr      = (int*)alloc((size_t)E * 4);
    float* h        = (float*)alloc((size_t)N * 128 * 4);
    float* agg      = (float*)alloc((size_t)N * 128 * 4);
    if (off > ws_size) return;  // workspace too small: fail cleanly

    int nb1 = (N + 1023) / 1024;

    hipMemsetAsync(degi, 0, (size_t)N * 4, stream);
    count_deg<<<(E + 255) / 256, 256, 0, stream>>>(dst, E, degi);
    scan_blocks<<<nb1, 256, 0, stream>>>(degi, N, row_ptr, partials);
    scan_partials<<<1, 128, 0, stream>>>(partials, nb1);
    finalize_rows<<<(N + 255) / 256, 256, 0, stream>>>(degi, N, row_ptr, partials, cursor, dinv);
    fill_csr<<<(E + 255) / 256, 256, 0, stream>>>(src, dst, E, cursor, csr);

    // h = x @ W1
    sgemm128<0><<<(N + 127) / 128, 256, 0, stream>>>(x, N, W1, nullptr, nullptr, nullptr, h, nullptr);
    // h1 = relu(A @ h + b1)   -> agg
    gather_rows<1><<<(N * 64 + 255) / 256, 256, 0, stream>>>(h, dinv, row_ptr, csr, b1, agg, N);
    // g = A @ h1              -> h (reuse)
    gather_rows<0><<<(N * 64 + 255) / 256, 256, 0, stream>>>(agg, dinv, row_ptr, csr, nullptr, h, N);
    // mu | logstd = g @ [W_mu|W_ls] + [b_mu|b_ls]  -> d_out halves
    sgemm128<1><<<(N + 127) / 128, 256, 0, stream>>>(h, N, Wmu, Wls, bmu, bls, out, out + (size_t)N * 64);
}

// Round 2
// 534.908 us; speedup vs baseline: 1.1865x; 1.1865x over previous
//
#include <hip/hip_runtime.h>

// ---------------------------------------------------------------------------
// VariationalGCNEncoder on MI355X
//   deg/CSR build (int atomics) -> dinv, packed csr2 = (src, w=dinv[s]*dinv[d])
//   h   = x @ W1                         (SGEMM, f32)
//   h1  = relu(A_norm @ h + b1)          (gather, 8x unrolled, bias+relu fused)
//   g   = A_norm @ h1                    (gather)    [shared by mu & logstd]
//   mu  = g @ W_mu + b_mu ; ls = g @ W_ls + b_ls     (SGEMM, split epilogue)
// ---------------------------------------------------------------------------

__global__ void count_deg(const int* __restrict__ dst, int E, int* __restrict__ degi) {
    int i = blockIdx.x * blockDim.x + threadIdx.x;
    if (i < E) atomicAdd(&degi[dst[i]], 1);
}

// 256 threads, 1024 elements per block. Writes chunk-local inclusive scan into
// row_ptr[ix+1], block totals into partials[].
__global__ __launch_bounds__(256) void scan_blocks(const int* __restrict__ degi, int n,
                                                   int* __restrict__ row_ptr,
                                                   int* __restrict__ partials) {
    __shared__ int sh[256];
    int t = threadIdx.x;
    int base = blockIdx.x * 1024;
    int idx0 = base + t * 4;
    int v[4];
#pragma unroll
    for (int i = 0; i < 4; ++i) {
        int ix = idx0 + i;
        v[i] = (ix < n) ? degi[ix] : 0;
    }
    int s = v[0] + v[1] + v[2] + v[3];
    sh[t] = s;
    __syncthreads();
    for (int off = 1; off < 256; off <<= 1) {
        int x = (t >= off) ? sh[t - off] : 0;
        __syncthreads();
        sh[t] += x;
        __syncthreads();
    }
    int run = sh[t] - s;  // exclusive prefix of this thread inside block
#pragma unroll
    for (int i = 0; i < 4; ++i) {
        int ix = idx0 + i;
        run += v[i];
        if (ix < n) row_ptr[ix + 1] = run;
    }
    if (t == 255) partials[blockIdx.x] = sh[255];
}

// nb <= 128. Exclusive scan of block totals, in place.
__global__ void scan_partials(int* __restrict__ partials, int nb) {
    __shared__ int sh[128];
    int t = threadIdx.x;
    int v = (t < nb) ? partials[t] : 0;
    sh[t] = v;
    __syncthreads();
    for (int off = 1; off < 128; off <<= 1) {
        int x = (t >= off) ? sh[t - off] : 0;
        __syncthreads();
        sh[t] += x;
        __syncthreads();
    }
    if (t < nb) partials[t] = sh[t] - v;
}

__global__ void finalize_rows(const int* __restrict__ degi, int n,
                              int* __restrict__ row_ptr, const int* __restrict__ partials,
                              int* __restrict__ cursor, float* __restrict__ dinv) {
    int i = blockIdx.x * blockDim.x + threadIdx.x;
    if (i == 0) row_ptr[0] = 0;
    if (i < n) {
        int p = partials[i >> 10];
        int rp1 = row_ptr[i + 1] + p;
        row_ptr[i + 1] = rp1;
        cursor[i] = rp1 - degi[i];                 // == final row_ptr[i]
        dinv[i] = rsqrtf((float)(degi[i] + 1));    // +1: self-loop
    }
}

// Packs (src, w = dinv[src]*dinv[dst]) into one 8B record so the gather's
// inner loop has a 2-stage load chain (edge record -> row) instead of 3.
__global__ void fill_csr(const int* __restrict__ src, const int* __restrict__ dst, int E,
                         const float* __restrict__ dinv,
                         int* __restrict__ cursor, long long* __restrict__ csr2) {
    int i = blockIdx.x * blockDim.x + threadIdx.x;
    if (i < E) {
        int d = dst[i];
        int s = src[i];
        int p = atomicAdd(&cursor[d], 1);
        float w = dinv[s] * dinv[d];
        long long rec = (long long)(unsigned)s |
                        ((long long)(unsigned)__float_as_uint(w) << 32);
        csr2[p] = rec;
    }
}

// One wave per destination node; lane l holds channels 2l, 2l+1.
// 8x unrolled with masked tail: 8 edge records then 8 independent 512B row
// loads in flight per wave. FUSE=1: out = relu(acc + bias). Self-loop folded
// into the init.
template <int FUSE>
__global__ __launch_bounds__(256) void gather_rows(const float* __restrict__ h,
                                                   const float* __restrict__ dinv,
                                                   const int* __restrict__ row_ptr,
                                                   const long long* __restrict__ csr2,
                                                   const float* __restrict__ bias,
                                                   float* __restrict__ out, int n) {
    int wid = (blockIdx.x * 256 + threadIdx.x) >> 6;
    int lane = threadIdx.x & 63;
    if (wid >= n) return;
    float dv = dinv[wid];
    int beg = row_ptr[wid];
    int end = row_ptr[wid + 1];
    float2 a = ((const float2*)(h + (size_t)wid * 128))[lane];
    float sw = dv * dv;  // self-loop norm
    float accx = a.x * sw, accy = a.y * sw;

#pragma unroll 1
    for (int j = beg; j < end; j += 8) {
        long long e[8];
#pragma unroll
        for (int k = 0; k < 8; ++k) {
            int idx = j + k;
            e[k] = csr2[idx < end ? idx : beg];
        }
        float2 b[8];
        float w[8];
#pragma unroll
        for (int k = 0; k < 8; ++k) {
            int s = (int)(unsigned)(e[k] & 0xffffffffLL);
            w[k] = __uint_as_float((unsigned)(e[k] >> 32));
            if (j + k >= end) w[k] = 0.0f;
            b[k] = ((const float2*)(h + (size_t)s * 128))[lane];
        }
#pragma unroll
        for (int k = 0; k < 8; ++k) {
            accx = fmaf(w[k], b[k].x, accx);
            accy = fmaf(w[k], b[k].y, accy);
        }
    }

    if (FUSE) {
        float2 bb = ((const float2*)bias)[lane];
        accx = fmaxf(accx + bb.x, 0.0f);
        accy = fmaxf(accy + bb.y, 0.0f);
    }
    ((float2*)(out + (size_t)wid * 128))[lane] = make_float2(accx, accy);
}

// C[M,128] = A[M,128] @ B[128,128]; 256 thr, BM=BN=128, BK=32, 8x8 micro-tile
// split as rows {ty*4+i, 64+ty*4+i} x cols {tx*4+j, 64+tx*4+j}.
// MODE 0: B = B0 (128 wide), plain write to C0[M,128].
// MODE 1: B cols 0-63 from B0(=W_mu), 64-127 from B1(=W_ls); epilogue adds
//         bias and writes halves to C0 (mu) and C1 (logstd), each [M,64].
template <int MODE>
__global__ __launch_bounds__(256) void sgemm128(const float* __restrict__ A, int M,
                                                const float* __restrict__ B0,
                                                const float* __restrict__ B1,
                                                const float* __restrict__ bias0,
                                                const float* __restrict__ bias1,
                                                float* __restrict__ C0,
                                                float* __restrict__ C1) {
    __shared__ float As[32][132];
    __shared__ float Bs[32][128];
    int tid = threadIdx.x;
    int row0 = blockIdx.x * 128;
    int tx = tid & 15, ty = tid >> 4;
    float acc[8][8] = {};
    for (int k0 = 0; k0 < 128; k0 += 32) {
#pragma unroll
        for (int i = 0; i < 4; ++i) {
            int idx = tid + i * 256;       // 0..1023
            int r = idx >> 3;              // 0..127
            int c4 = (idx & 7) << 2;       // 0..28
            int grow = row0 + r;
            float4 v = make_float4(0.f, 0.f, 0.f, 0.f);
            if (grow < M) v = *(const float4*)(A + (size_t)grow * 128 + k0 + c4);
            As[c4 + 0][r] = v.x;
            As[c4 + 1][r] = v.y;
            As[c4 + 2][r] = v.z;
            As[c4 + 3][r] = v.w;
        }
#pragma unroll
        for (int i = 0; i < 4; ++i) {
            int idx = tid + i * 256;
            int r = idx >> 5;              // 0..31
            int c4 = (idx & 31) << 2;      // 0..124
            const float* bp;
            if (MODE == 0) {
                bp = B0 + (size_t)(k0 + r) * 128 + c4;
            } else {
                bp = (c4 < 64) ? (B0 + (size_t)(k0 + r) * 64 + c4)
                               : (B1 + (size_t)(k0 + r) * 64 + (c4 - 64));
            }
            *(float4*)&Bs[r][c4] = *(const float4*)bp;
        }
        __syncthreads();
#pragma unroll
        for (int k = 0; k < 32; ++k) {
            float a[8], b[8];
            *(float4*)&a[0] = *(const float4*)&As[k][ty * 4];
            *(float4*)&a[4] = *(const float4*)&As[k][64 + ty * 4];
            *(float4*)&b[0] = *(const float4*)&Bs[k][tx * 4];
            *(float4*)&b[4] = *(const float4*)&Bs[k][64 + tx * 4];
#pragma unroll
            for (int i = 0; i < 8; ++i)
#pragma unroll
                for (int j = 0; j < 8; ++j) acc[i][j] = fmaf(a[i], b[j], acc[i][j]);
        }
        __syncthreads();
    }
#pragma unroll
    for (int ig = 0; ig < 2; ++ig) {
#pragma unroll
        for (int ii = 0; ii < 4; ++ii) {
            int i = ig * 4 + ii;
            int grow = row0 + ig * 64 + ty * 4 + ii;
            if (grow >= M) continue;
#pragma unroll
            for (int jg = 0; jg < 2; ++jg) {
                float4 v = make_float4(acc[i][jg * 4 + 0], acc[i][jg * 4 + 1],
                                       acc[i][jg * 4 + 2], acc[i][jg * 4 + 3]);
                if (MODE == 0) {
                    *(float4*)(C0 + (size_t)grow * 128 + jg * 64 + tx * 4) = v;
                } else {
                    int c = tx * 4;
                    const float* bs = (jg == 0) ? bias0 : bias1;
                    v.x += bs[c + 0];
                    v.y += bs[c + 1];
                    v.z += bs[c + 2];
                    v.w += bs[c + 3];
                    float* cp = ((jg == 0) ? C0 : C1) + (size_t)grow * 64 + c;
                    *(float4*)cp = v;
                }
            }
        }
    }
}

extern "C" void kernel_launch(void* const* d_in, const int* in_sizes, int n_in,
                              void* d_out, int out_size, void* d_ws, size_t ws_size,
                              hipStream_t stream) {
    const float* x   = (const float*)d_in[0];
    const int*  eidx = (const int*)d_in[1];
    const float* W1  = (const float*)d_in[2];
    const float* b1  = (const float*)d_in[3];
    const float* Wmu = (const float*)d_in[4];
    const float* bmu = (const float*)d_in[5];
    const float* Wls = (const float*)d_in[6];
    const float* bls = (const float*)d_in[7];
    float* out = (float*)d_out;

    const int N = in_sizes[0] / 128;  // 100000
    const int E = in_sizes[1] / 2;    // 1600000
    const int* src = eidx;
    const int* dst = eidx + E;

    char* w = (char*)d_ws;
    size_t off = 0;
    auto alloc = [&](size_t bytes) {
        void* p = w + off;
        off += (bytes + 255) & ~(size_t)255;
        return p;
    };
    int*       degi     = (int*)alloc((size_t)N * 4);
    int*       row_ptr  = (int*)alloc((size_t)(N + 1) * 4);
    int*       cursor   = (int*)alloc((size_t)N * 4);
    float*     dinv     = (float*)alloc((size_t)N * 4);
    int*       partials = (int*)alloc(512);
    long long* csr2     = (long long*)alloc((size_t)E * 8);
    float*     h        = (float*)alloc((size_t)N * 128 * 4);
    float*     agg      = (float*)alloc((size_t)N * 128 * 4);
    if (off > ws_size) return;  // workspace too small: fail cleanly

    int nb1 = (N + 1023) / 1024;

    hipMemsetAsync(degi, 0, (size_t)N * 4, stream);
    count_deg<<<(E + 255) / 256, 256, 0, stream>>>(dst, E, degi);
    scan_blocks<<<nb1, 256, 0, stream>>>(degi, N, row_ptr, partials);
    scan_partials<<<1, 128, 0, stream>>>(partials, nb1);
    finalize_rows<<<(N + 255) / 256, 256, 0, stream>>>(degi, N, row_ptr, partials, cursor, dinv);
    fill_csr<<<(E + 255) / 256, 256, 0, stream>>>(src, dst, E, dinv, cursor, csr2);

    // h = x @ W1
    sgemm128<0><<<(N + 127) / 128, 256, 0, stream>>>(x, N, W1, nullptr, nullptr, nullptr, h, nullptr);
    // h1 = relu(A @ h + b1)   -> agg
    gather_rows<1><<<(N * 64 + 255) / 256, 256, 0, stream>>>(h, dinv, row_ptr, csr2, b1, agg, N);
    // g = A @ h1              -> h (reuse)
    gather_rows<0><<<(N * 64 + 255) / 256, 256, 0, stream>>>(agg, dinv, row_ptr, csr2, nullptr, h, N);
    // mu | logstd = g @ [W_mu|W_ls] + [b_mu|b_ls]  -> d_out halves
    sgemm128<1><<<(N + 127) / 128, 256, 0, stream>>>(h, N, Wmu, Wls, bmu, bls, out, out + (size_t)N * 64);
}

// Round 3
// 414.272 us; speedup vs baseline: 1.5320x; 1.2912x over previous
//
#include <hip/hip_runtime.h>
#include <hip/hip_fp16.h>

// ---------------------------------------------------------------------------
// VariationalGCNEncoder on MI355X
//   deg/CSR build (int atomics) -> dinv, packed csr2 = (src, w=dinv[s]*dinv[d])
//   h   = x @ W1              (SGEMM f32, epilogue stores fp16)
//   h1  = relu(A @ h + b1)    (gather fp16->fp16, 8x unrolled, bias+relu fused)
//   g   = A @ h1              (gather fp16->f32)   [shared by mu & logstd]
//   mu | logstd = g @ [W_mu|W_ls] + bias           (SGEMM f32, split epilogue)
// Random-read payload halved vs R2: gathered rows are fp16 (256 B/row).
// ---------------------------------------------------------------------------

__global__ void count_deg(const int* __restrict__ dst, int E, int* __restrict__ degi) {
    int i = blockIdx.x * blockDim.x + threadIdx.x;
    if (i < E) atomicAdd(&degi[dst[i]], 1);
}

// 256 threads, 1024 elements per block. Writes chunk-local inclusive scan into
// row_ptr[ix+1], block totals into partials[].
__global__ __launch_bounds__(256) void scan_blocks(const int* __restrict__ degi, int n,
                                                   int* __restrict__ row_ptr,
                                                   int* __restrict__ partials) {
    __shared__ int sh[256];
    int t = threadIdx.x;
    int base = blockIdx.x * 1024;
    int idx0 = base + t * 4;
    int v[4];
#pragma unroll
    for (int i = 0; i < 4; ++i) {
        int ix = idx0 + i;
        v[i] = (ix < n) ? degi[ix] : 0;
    }
    int s = v[0] + v[1] + v[2] + v[3];
    sh[t] = s;
    __syncthreads();
    for (int off = 1; off < 256; off <<= 1) {
        int x = (t >= off) ? sh[t - off] : 0;
        __syncthreads();
        sh[t] += x;
        __syncthreads();
    }
    int run = sh[t] - s;  // exclusive prefix of this thread inside block
#pragma unroll
    for (int i = 0; i < 4; ++i) {
        int ix = idx0 + i;
        run += v[i];
        if (ix < n) row_ptr[ix + 1] = run;
    }
    if (t == 255) partials[blockIdx.x] = sh[255];
}

// nb <= 128. Exclusive scan of block totals, in place.
__global__ void scan_partials(int* __restrict__ partials, int nb) {
    __shared__ int sh[128];
    int t = threadIdx.x;
    int v = (t < nb) ? partials[t] : 0;
    sh[t] = v;
    __syncthreads();
    for (int off = 1; off < 128; off <<= 1) {
        int x = (t >= off) ? sh[t - off] : 0;
        __syncthreads();
        sh[t] += x;
        __syncthreads();
    }
    if (t < nb) partials[t] = sh[t] - v;
}

__global__ void finalize_rows(const int* __restrict__ degi, int n,
                              int* __restrict__ row_ptr, const int* __restrict__ partials,
                              int* __restrict__ cursor, float* __restrict__ dinv) {
    int i = blockIdx.x * blockDim.x + threadIdx.x;
    if (i == 0) row_ptr[0] = 0;
    if (i < n) {
        int p = partials[i >> 10];
        int rp1 = row_ptr[i + 1] + p;
        row_ptr[i + 1] = rp1;
        cursor[i] = rp1 - degi[i];                 // == final row_ptr[i]
        dinv[i] = rsqrtf((float)(degi[i] + 1));    // +1: self-loop
    }
}

// Packs (src, w = dinv[src]*dinv[dst]) into one 8B record so the gather's
// inner loop has a 2-stage load chain (edge record -> row).
__global__ void fill_csr(const int* __restrict__ src, const int* __restrict__ dst, int E,
                         const float* __restrict__ dinv,
                         int* __restrict__ cursor, long long* __restrict__ csr2) {
    int i = blockIdx.x * blockDim.x + threadIdx.x;
    if (i < E) {
        int d = dst[i];
        int s = src[i];
        int p = atomicAdd(&cursor[d], 1);
        float w = dinv[s] * dinv[d];
        long long rec = (long long)(unsigned)s |
                        ((long long)(unsigned)__float_as_uint(w) << 32);
        csr2[p] = rec;
    }
}

// One wave per destination node; lane l holds channels 2l, 2l+1 (fp16 in,
// f32 accumulate). 8x unrolled with masked tail: 8 edge records then 8
// independent 256B row loads in flight per wave.
// FUSE=1: out = relu(acc + bias). OUT_F32: store float2, else __half2.
// Self-loop folded into the init.
template <int FUSE, int OUT_F32>
__global__ __launch_bounds__(256) void gather_rows(const __half* __restrict__ h,
                                                   const float* __restrict__ dinv,
                                                   const int* __restrict__ row_ptr,
                                                   const long long* __restrict__ csr2,
                                                   const float* __restrict__ bias,
                                                   void* __restrict__ out, int n) {
    int wid = (blockIdx.x * 256 + threadIdx.x) >> 6;
    int lane = threadIdx.x & 63;
    if (wid >= n) return;
    float dv = dinv[wid];
    int beg = row_ptr[wid];
    int end = row_ptr[wid + 1];
    float2 a = __half22float2(((const __half2*)(h + (size_t)wid * 128))[lane]);
    float sw = dv * dv;  // self-loop norm
    float accx = a.x * sw, accy = a.y * sw;

#pragma unroll 1
    for (int j = beg; j < end; j += 8) {
        long long e[8];
#pragma unroll
        for (int k = 0; k < 8; ++k) {
            int idx = j + k;
            e[k] = csr2[idx < end ? idx : beg];
        }
        __half2 b[8];
        float w[8];
#pragma unroll
        for (int k = 0; k < 8; ++k) {
            int s = (int)(unsigned)(e[k] & 0xffffffffLL);
            w[k] = __uint_as_float((unsigned)(e[k] >> 32));
            if (j + k >= end) w[k] = 0.0f;
            b[k] = ((const __half2*)(h + (size_t)s * 128))[lane];
        }
#pragma unroll
        for (int k = 0; k < 8; ++k) {
            float2 bf = __half22float2(b[k]);
            accx = fmaf(w[k], bf.x, accx);
            accy = fmaf(w[k], bf.y, accy);
        }
    }

    if (FUSE) {
        float2 bb = ((const float2*)bias)[lane];
        accx = fmaxf(accx + bb.x, 0.0f);
        accy = fmaxf(accy + bb.y, 0.0f);
    }
    if (OUT_F32) {
        ((float2*)out)[(size_t)wid * 64 + lane] = make_float2(accx, accy);
    } else {
        ((__half2*)out)[(size_t)wid * 64 + lane] = __floats2half2_rn(accx, accy);
    }
}

// C[M,128] = A[M,128] @ B[128,128]; 256 thr, BM=BN=128, BK=32, 8x8 micro-tile
// split as rows {ty*4+i, 64+ty*4+i} x cols {tx*4+j, 64+tx*4+j}.
// MODE 0: B = B0 (128 wide), write C0 as fp16 [M,128].
// MODE 1: B cols 0-63 from B0(=W_mu), 64-127 from B1(=W_ls); epilogue adds
//         bias and writes f32 halves to C0 (mu) and C1 (logstd), each [M,64].
template <int MODE>
__global__ __launch_bounds__(256) void sgemm128(const float* __restrict__ A, int M,
                                                const float* __restrict__ B0,
                                                const float* __restrict__ B1,
                                                const float* __restrict__ bias0,
                                                const float* __restrict__ bias1,
                                                void* __restrict__ C0v,
                                                float* __restrict__ C1) {
    __shared__ float As[32][132];
    __shared__ float Bs[32][128];
    int tid = threadIdx.x;
    int row0 = blockIdx.x * 128;
    int tx = tid & 15, ty = tid >> 4;
    float acc[8][8] = {};
    for (int k0 = 0; k0 < 128; k0 += 32) {
#pragma unroll
        for (int i = 0; i < 4; ++i) {
            int idx = tid + i * 256;       // 0..1023
            int r = idx >> 3;              // 0..127
            int c4 = (idx & 7) << 2;       // 0..28
            int grow = row0 + r;
            float4 v = make_float4(0.f, 0.f, 0.f, 0.f);
            if (grow < M) v = *(const float4*)(A + (size_t)grow * 128 + k0 + c4);
            As[c4 + 0][r] = v.x;
            As[c4 + 1][r] = v.y;
            As[c4 + 2][r] = v.z;
            As[c4 + 3][r] = v.w;
        }
#pragma unroll
        for (int i = 0; i < 4; ++i) {
            int idx = tid + i * 256;
            int r = idx >> 5;              // 0..31
            int c4 = (idx & 31) << 2;      // 0..124
            const float* bp;
            if (MODE == 0) {
                bp = B0 + (size_t)(k0 + r) * 128 + c4;
            } else {
                bp = (c4 < 64) ? (B0 + (size_t)(k0 + r) * 64 + c4)
                               : (B1 + (size_t)(k0 + r) * 64 + (c4 - 64));
            }
            *(float4*)&Bs[r][c4] = *(const float4*)bp;
        }
        __syncthreads();
#pragma unroll
        for (int k = 0; k < 32; ++k) {
            float a[8], b[8];
            *(float4*)&a[0] = *(const float4*)&As[k][ty * 4];
            *(float4*)&a[4] = *(const float4*)&As[k][64 + ty * 4];
            *(float4*)&b[0] = *(const float4*)&Bs[k][tx * 4];
            *(float4*)&b[4] = *(const float4*)&Bs[k][64 + tx * 4];
#pragma unroll
            for (int i = 0; i < 8; ++i)
#pragma unroll
                for (int j = 0; j < 8; ++j) acc[i][j] = fmaf(a[i], b[j], acc[i][j]);
        }
        __syncthreads();
    }
#pragma unroll
    for (int ig = 0; ig < 2; ++ig) {
#pragma unroll
        for (int ii = 0; ii < 4; ++ii) {
            int i = ig * 4 + ii;
            int grow = row0 + ig * 64 + ty * 4 + ii;
            if (grow >= M) continue;
#pragma unroll
            for (int jg = 0; jg < 2; ++jg) {
                float4 v = make_float4(acc[i][jg * 4 + 0], acc[i][jg * 4 + 1],
                                       acc[i][jg * 4 + 2], acc[i][jg * 4 + 3]);
                if (MODE == 0) {
                    __half* cp = (__half*)C0v + (size_t)grow * 128 + jg * 64 + tx * 4;
                    *(__half2*)(cp + 0) = __floats2half2_rn(v.x, v.y);
                    *(__half2*)(cp + 2) = __floats2half2_rn(v.z, v.w);
                } else {
                    int c = tx * 4;
                    const float* bs = (jg == 0) ? bias0 : bias1;
                    v.x += bs[c + 0];
                    v.y += bs[c + 1];
                    v.z += bs[c + 2];
                    v.w += bs[c + 3];
                    float* cp = ((jg == 0) ? (float*)C0v : C1) + (size_t)grow * 64 + c;
                    *(float4*)cp = v;
                }
            }
        }
    }
}

extern "C" void kernel_launch(void* const* d_in, const int* in_sizes, int n_in,
                              void* d_out, int out_size, void* d_ws, size_t ws_size,
                              hipStream_t stream) {
    const float* x   = (const float*)d_in[0];
    const int*  eidx = (const int*)d_in[1];
    const float* W1  = (const float*)d_in[2];
    const float* b1  = (const float*)d_in[3];
    const float* Wmu = (const float*)d_in[4];
    const float* bmu = (const float*)d_in[5];
    const float* Wls = (const float*)d_in[6];
    const float* bls = (const float*)d_in[7];
    float* out = (float*)d_out;

    const int N = in_sizes[0] / 128;  // 100000
    const int E = in_sizes[1] / 2;    // 1600000
    const int* src = eidx;
    const int* dst = eidx + E;

    char* w = (char*)d_ws;
    size_t off = 0;
    auto alloc = [&](size_t bytes) {
        void* p = w + off;
        off += (bytes + 255) & ~(size_t)255;
        return p;
    };
    int*       degi     = (int*)alloc((size_t)N * 4);
    int*       row_ptr  = (int*)alloc((size_t)(N + 1) * 4);
    int*       cursor   = (int*)alloc((size_t)N * 4);
    float*     dinv     = (float*)alloc((size_t)N * 4);
    int*       partials = (int*)alloc(512);
    long long* csr2     = (long long*)alloc((size_t)E * 8);
    __half*    h        = (__half*)alloc((size_t)N * 128 * 2);
    __half*    h1       = (__half*)alloc((size_t)N * 128 * 2);
    float*     g        = (float*)alloc((size_t)N * 128 * 4);
    if (off > ws_size) return;  // workspace too small: fail cleanly

    int nb1 = (N + 1023) / 1024;

    hipMemsetAsync(degi, 0, (size_t)N * 4, stream);
    count_deg<<<(E + 255) / 256, 256, 0, stream>>>(dst, E, degi);
    scan_blocks<<<nb1, 256, 0, stream>>>(degi, N, row_ptr, partials);
    scan_partials<<<1, 128, 0, stream>>>(partials, nb1);
    finalize_rows<<<(N + 255) / 256, 256, 0, stream>>>(degi, N, row_ptr, partials, cursor, dinv);
    fill_csr<<<(E + 255) / 256, 256, 0, stream>>>(src, dst, E, dinv, cursor, csr2);

    // h = x @ W1   (fp16 out)
    sgemm128<0><<<(N + 127) / 128, 256, 0, stream>>>(x, N, W1, nullptr, nullptr, nullptr, h, nullptr);
    // h1 = relu(A @ h + b1)   (fp16 out)
    gather_rows<1, 0><<<(N * 64 + 255) / 256, 256, 0, stream>>>(h, dinv, row_ptr, csr2, b1, h1, N);
    // g = A @ h1              (f32 out)
    gather_rows<0, 1><<<(N * 64 + 255) / 256, 256, 0, stream>>>(h1, dinv, row_ptr, csr2, nullptr, g, N);
    // mu | logstd = g @ [W_mu|W_ls] + [b_mu|b_ls]  -> d_out halves
    sgemm128<1><<<(N + 127) / 128, 256, 0, stream>>>(g, N, Wmu, Wls, bmu, bls, out, out + (size_t)N * 64);
}

// Round 4
// 378.195 us; speedup vs baseline: 1.6781x; 1.0954x over previous
//
#include <hip/hip_runtime.h>
#include <hip/hip_fp16.h>

// ---------------------------------------------------------------------------
// VariationalGCNEncoder on MI355X
//   bucket-partition edges by dst (deterministic 2-pass radix, 1024 buckets)
//   -> count/scan/finalize/fill on partitioned stream (window-local atomics,
//      no HBM write amplification)
//   h   = x @ W1              (SGEMM f32, epilogue stores fp16)
//   h1  = relu(A @ h + b1)    (gather fp16->fp16, 8x unrolled, bias+relu fused)
//   g   = A @ h1              (gather fp16->f32)   [shared by mu & logstd]
//   mu | logstd = g @ [W_mu|W_ls] + bias           (SGEMM f32, split epilogue)
// ---------------------------------------------------------------------------

#define NBUCKET 1024
#define NPB 512  // partition blocks; chunk = ceil(E/NPB)

// ---- partition pass 1: per-block bucket histogram --------------------------
__global__ __launch_bounds__(256) void hist_pass(const int* __restrict__ dst, int E,
                                                 int chunk, int shift,
                                                 int* __restrict__ blk_hist) {
    __shared__ int hist[NBUCKET];
    for (int i = threadIdx.x; i < NBUCKET; i += 256) hist[i] = 0;
    __syncthreads();
    int b = blockIdx.x;
    int beg = b * chunk;
    int end = beg + chunk; if (end > E) end = E;
    for (int i = beg + threadIdx.x; i < end; i += 256)
        atomicAdd(&hist[dst[i] >> shift], 1);
    __syncthreads();
    for (int i = threadIdx.x; i < NBUCKET; i += 256)
        blk_hist[(size_t)b * NBUCKET + i] = hist[i];
}

// ---- partition pass 2: per-bucket column scan (one block per bucket) -------
__global__ __launch_bounds__(256) void col_scan(const int* __restrict__ blk_hist,
                                                int* __restrict__ blk_base,
                                                int* __restrict__ bucket_total) {
    __shared__ int sh[256];
    int q = blockIdx.x, t = threadIdx.x;
    int v0 = blk_hist[(size_t)(2 * t) * NBUCKET + q];
    int v1 = blk_hist[(size_t)(2 * t + 1) * NBUCKET + q];
    int s = v0 + v1;
    sh[t] = s;
    __syncthreads();
    for (int off = 1; off < 256; off <<= 1) {
        int x = (t >= off) ? sh[t - off] : 0;
        __syncthreads();
        sh[t] += x;
        __syncthreads();
    }
    int pre = sh[t] - s;
    blk_base[(size_t)(2 * t) * NBUCKET + q] = pre;
    blk_base[(size_t)(2 * t + 1) * NBUCKET + q] = pre + v0;
    if (t == 255) bucket_total[q] = sh[255];
}

// ---- exclusive scan of 1024 bucket totals (single block) -------------------
__global__ __launch_bounds__(256) void scan_bucket(const int* __restrict__ total,
                                                   int* __restrict__ base) {
    __shared__ int sh[256];
    int t = threadIdx.x;
    int idx0 = t * 4;
    int v[4];
#pragma unroll
    for (int k = 0; k < 4; ++k) v[k] = total[idx0 + k];
    int s = v[0] + v[1] + v[2] + v[3];
    sh[t] = s;
    __syncthreads();
    for (int off = 1; off < 256; off <<= 1) {
        int x = (t >= off) ? sh[t - off] : 0;
        __syncthreads();
        sh[t] += x;
        __syncthreads();
    }
    int run = sh[t] - s;
#pragma unroll
    for (int k = 0; k < 4; ++k) {
        base[idx0 + k] = run;
        run += v[k];
    }
}

// ---- partition pass 3: scatter (dst,src) pairs into bucket-ordered part[] --
__global__ __launch_bounds__(256) void scatter_pass(const int* __restrict__ src,
                                                    const int* __restrict__ dst, int E,
                                                    int chunk, int shift,
                                                    const int* __restrict__ bucket_base,
                                                    const int* __restrict__ blk_base,
                                                    long long* __restrict__ part) {
    __shared__ int cur[NBUCKET];
    int b = blockIdx.x;
    for (int i = threadIdx.x; i < NBUCKET; i += 256)
        cur[i] = bucket_base[i] + blk_base[(size_t)b * NBUCKET + i];
    __syncthreads();
    int beg = b * chunk;
    int end = beg + chunk; if (end > E) end = E;
    for (int i = beg + threadIdx.x; i < end; i += 256) {
        int d = dst[i], s = src[i];
        int q = d >> shift;
        int p = atomicAdd(&cur[q], 1);
        part[p] = ((long long)(unsigned)d << 32) | (unsigned)s;
    }
}

// ---- degree count over the partitioned stream (window-local atomics) -------
__global__ void count_deg2(const long long* __restrict__ part, int E,
                           int* __restrict__ degi) {
    int i = blockIdx.x * blockDim.x + threadIdx.x;
    if (i < E) {
        int d = (int)(unsigned)((unsigned long long)part[i] >> 32);
        atomicAdd(&degi[d], 1);
    }
}

// 256 threads, 1024 elements per block. Chunk-local inclusive scan into
// row_ptr[ix+1], block totals into partials[].
__global__ __launch_bounds__(256) void scan_blocks(const int* __restrict__ degi, int n,
                                                   int* __restrict__ row_ptr,
                                                   int* __restrict__ partials) {
    __shared__ int sh[256];
    int t = threadIdx.x;
    int base = blockIdx.x * 1024;
    int idx0 = base + t * 4;
    int v[4];
#pragma unroll
    for (int i = 0; i < 4; ++i) {
        int ix = idx0 + i;
        v[i] = (ix < n) ? degi[ix] : 0;
    }
    int s = v[0] + v[1] + v[2] + v[3];
    sh[t] = s;
    __syncthreads();
    for (int off = 1; off < 256; off <<= 1) {
        int x = (t >= off) ? sh[t - off] : 0;
        __syncthreads();
        sh[t] += x;
        __syncthreads();
    }
    int run = sh[t] - s;
#pragma unroll
    for (int i = 0; i < 4; ++i) {
        int ix = idx0 + i;
        run += v[i];
        if (ix < n) row_ptr[ix + 1] = run;
    }
    if (t == 255) partials[blockIdx.x] = sh[255];
}

// nb <= 128. Exclusive scan of block totals, in place.
__global__ void scan_partials(int* __restrict__ partials, int nb) {
    __shared__ int sh[128];
    int t = threadIdx.x;
    int v = (t < nb) ? partials[t] : 0;
    sh[t] = v;
    __syncthreads();
    for (int off = 1; off < 128; off <<= 1) {
        int x = (t >= off) ? sh[t - off] : 0;
        __syncthreads();
        sh[t] += x;
        __syncthreads();
    }
    if (t < nb) partials[t] = sh[t] - v;
}

__global__ void finalize_rows(const int* __restrict__ degi, int n,
                              int* __restrict__ row_ptr, const int* __restrict__ partials,
                              int* __restrict__ cursor, float* __restrict__ dinv) {
    int i = blockIdx.x * blockDim.x + threadIdx.x;
    if (i == 0) row_ptr[0] = 0;
    if (i < n) {
        int p = partials[i >> 10];
        int rp1 = row_ptr[i + 1] + p;
        row_ptr[i + 1] = rp1;
        cursor[i] = rp1 - degi[i];                 // == final row_ptr[i]
        dinv[i] = rsqrtf((float)(degi[i] + 1));    // +1: self-loop
    }
}

// ---- CSR fill from partitioned pairs: window-local cursor + csr2 writes ----
__global__ void fill_csr2(const long long* __restrict__ part, int E,
                          const float* __restrict__ dinv,
                          int* __restrict__ cursor, long long* __restrict__ csr2) {
    int i = blockIdx.x * blockDim.x + threadIdx.x;
    if (i < E) {
        long long pr = part[i];
        int d = (int)(unsigned)((unsigned long long)pr >> 32);
        int s = (int)(unsigned)(pr & 0xffffffffLL);
        int p = atomicAdd(&cursor[d], 1);
        float w = dinv[s] * dinv[d];
        long long rec = (long long)(unsigned)s |
                        ((long long)(unsigned)__float_as_uint(w) << 32);
        csr2[p] = rec;
    }
}

// One wave per destination node; lane l holds channels 2l, 2l+1 (fp16 in,
// f32 accumulate). 8x unrolled with masked tail.
// FUSE=1: out = relu(acc + bias). OUT_F32: store float2, else __half2.
template <int FUSE, int OUT_F32>
__global__ __launch_bounds__(256) void gather_rows(const __half* __restrict__ h,
                                                   const float* __restrict__ dinv,
                                                   const int* __restrict__ row_ptr,
                                                   const long long* __restrict__ csr2,
                                                   const float* __restrict__ bias,
                                                   void* __restrict__ out, int n) {
    int wid = (blockIdx.x * 256 + threadIdx.x) >> 6;
    int lane = threadIdx.x & 63;
    if (wid >= n) return;
    float dv = dinv[wid];
    int beg = row_ptr[wid];
    int end = row_ptr[wid + 1];
    float2 a = __half22float2(((const __half2*)(h + (size_t)wid * 128))[lane]);
    float sw = dv * dv;  // self-loop norm
    float accx = a.x * sw, accy = a.y * sw;

#pragma unroll 1
    for (int j = beg; j < end; j += 8) {
        long long e[8];
#pragma unroll
        for (int k = 0; k < 8; ++k) {
            int idx = j + k;
            e[k] = csr2[idx < end ? idx : beg];
        }
        __half2 b[8];
        float w[8];
#pragma unroll
        for (int k = 0; k < 8; ++k) {
            int s = (int)(unsigned)(e[k] & 0xffffffffLL);
            w[k] = __uint_as_float((unsigned)(e[k] >> 32));
            if (j + k >= end) w[k] = 0.0f;
            b[k] = ((const __half2*)(h + (size_t)s * 128))[lane];
        }
#pragma unroll
        for (int k = 0; k < 8; ++k) {
            float2 bf = __half22float2(b[k]);
            accx = fmaf(w[k], bf.x, accx);
            accy = fmaf(w[k], bf.y, accy);
        }
    }

    if (FUSE) {
        float2 bb = ((const float2*)bias)[lane];
        accx = fmaxf(accx + bb.x, 0.0f);
        accy = fmaxf(accy + bb.y, 0.0f);
    }
    if (OUT_F32) {
        ((float2*)out)[(size_t)wid * 64 + lane] = make_float2(accx, accy);
    } else {
        ((__half2*)out)[(size_t)wid * 64 + lane] = __floats2half2_rn(accx, accy);
    }
}

// C[M,128] = A[M,128] @ B[128,128]; 256 thr, BM=BN=128, BK=32, 8x8 micro-tile.
// MODE 0: B = B0 (128 wide), write C0 as fp16 [M,128].
// MODE 1: B cols 0-63 from B0(=W_mu), 64-127 from B1(=W_ls); epilogue adds
//         bias and writes f32 halves to C0 (mu) and C1 (logstd), each [M,64].
template <int MODE>
__global__ __launch_bounds__(256) void sgemm128(const float* __restrict__ A, int M,
                                                const float* __restrict__ B0,
                                                const float* __restrict__ B1,
                                                const float* __restrict__ bias0,
                                                const float* __restrict__ bias1,
                                                void* __restrict__ C0v,
                                                float* __restrict__ C1) {
    __shared__ float As[32][132];
    __shared__ float Bs[32][128];
    int tid = threadIdx.x;
    int row0 = blockIdx.x * 128;
    int tx = tid & 15, ty = tid >> 4;
    float acc[8][8] = {};
    for (int k0 = 0; k0 < 128; k0 += 32) {
#pragma unroll
        for (int i = 0; i < 4; ++i) {
            int idx = tid + i * 256;       // 0..1023
            int r = idx >> 3;              // 0..127
            int c4 = (idx & 7) << 2;       // 0..28
            int grow = row0 + r;
            float4 v = make_float4(0.f, 0.f, 0.f, 0.f);
            if (grow < M) v = *(const float4*)(A + (size_t)grow * 128 + k0 + c4);
            As[c4 + 0][r] = v.x;
            As[c4 + 1][r] = v.y;
            As[c4 + 2][r] = v.z;
            As[c4 + 3][r] = v.w;
        }
#pragma unroll
        for (int i = 0; i < 4; ++i) {
            int idx = tid + i * 256;
            int r = idx >> 5;              // 0..31
            int c4 = (idx & 31) << 2;      // 0..124
            const float* bp;
            if (MODE == 0) {
                bp = B0 + (size_t)(k0 + r) * 128 + c4;
            } else {
                bp = (c4 < 64) ? (B0 + (size_t)(k0 + r) * 64 + c4)
                               : (B1 + (size_t)(k0 + r) * 64 + (c4 - 64));
            }
            *(float4*)&Bs[r][c4] = *(const float4*)bp;
        }
        __syncthreads();
#pragma unroll
        for (int k = 0; k < 32; ++k) {
            float a[8], b[8];
            *(float4*)&a[0] = *(const float4*)&As[k][ty * 4];
            *(float4*)&a[4] = *(const float4*)&As[k][64 + ty * 4];
            *(float4*)&b[0] = *(const float4*)&Bs[k][tx * 4];
            *(float4*)&b[4] = *(const float4*)&Bs[k][64 + tx * 4];
#pragma unroll
            for (int i = 0; i < 8; ++i)
#pragma unroll
                for (int j = 0; j < 8; ++j) acc[i][j] = fmaf(a[i], b[j], acc[i][j]);
        }
        __syncthreads();
    }
#pragma unroll
    for (int ig = 0; ig < 2; ++ig) {
#pragma unroll
        for (int ii = 0; ii < 4; ++ii) {
            int i = ig * 4 + ii;
            int grow = row0 + ig * 64 + ty * 4 + ii;
            if (grow >= M) continue;
#pragma unroll
            for (int jg = 0; jg < 2; ++jg) {
                float4 v = make_float4(acc[i][jg * 4 + 0], acc[i][jg * 4 + 1],
                                       acc[i][jg * 4 + 2], acc[i][jg * 4 + 3]);
                if (MODE == 0) {
                    __half* cp = (__half*)C0v + (size_t)grow * 128 + jg * 64 + tx * 4;
                    *(__half2*)(cp + 0) = __floats2half2_rn(v.x, v.y);
                    *(__half2*)(cp + 2) = __floats2half2_rn(v.z, v.w);
                } else {
                    int c = tx * 4;
                    const float* bs = (jg == 0) ? bias0 : bias1;
                    v.x += bs[c + 0];
                    v.y += bs[c + 1];
                    v.z += bs[c + 2];
                    v.w += bs[c + 3];
                    float* cp = ((jg == 0) ? (float*)C0v : C1) + (size_t)grow * 64 + c;
                    *(float4*)cp = v;
                }
            }
        }
    }
}

extern "C" void kernel_launch(void* const* d_in, const int* in_sizes, int n_in,
                              void* d_out, int out_size, void* d_ws, size_t ws_size,
                              hipStream_t stream) {
    const float* x   = (const float*)d_in[0];
    const int*  eidx = (const int*)d_in[1];
    const float* W1  = (const float*)d_in[2];
    const float* b1  = (const float*)d_in[3];
    const float* Wmu = (const float*)d_in[4];
    const float* bmu = (const float*)d_in[5];
    const float* Wls = (const float*)d_in[6];
    const float* bls = (const float*)d_in[7];
    float* out = (float*)d_out;

    const int N = in_sizes[0] / 128;  // 100000
    const int E = in_sizes[1] / 2;    // 1600000
    const int* src = eidx;
    const int* dst = eidx + E;

    int shift = 0;
    while (((N - 1) >> shift) >= NBUCKET) ++shift;  // N=100000 -> 7
    int chunk = (E + NPB - 1) / NPB;

    char* w = (char*)d_ws;
    size_t off = 0;
    auto alloc = [&](size_t bytes) {
        void* p = w + off;
        off += (bytes + 255) & ~(size_t)255;
        return p;
    };
    // persistent region
    int*       row_ptr      = (int*)alloc((size_t)(N + 1) * 4);
    int*       cursor       = (int*)alloc((size_t)N * 4);
    float*     dinv         = (float*)alloc((size_t)N * 4);
    int*       partials     = (int*)alloc(512);
    int*       bucket_total = (int*)alloc(NBUCKET * 4);
    int*       bucket_base  = (int*)alloc(NBUCKET * 4);
    long long* csr2         = (long long*)alloc((size_t)E * 8);
    __half*    h1           = (__half*)alloc((size_t)N * 128 * 2);
    // region D: early partition buffers, then h (fp16), then g (f32) — all
    // lifetimes disjoint (partition dead before sgemm1; h dead before gather2)
    size_t Dstart = off;
    int*       degi     = (int*)alloc((size_t)N * 4);
    int*       blk_hist = (int*)alloc((size_t)NPB * NBUCKET * 4);
    int*       blk_base = (int*)alloc((size_t)NPB * NBUCKET * 4);
    long long* part     = (long long*)alloc((size_t)E * 8);
    size_t Dearly_end = off;
    __half* h = (__half*)(w + Dstart);
    float*  g = (float*)(w + Dstart);
    size_t Dend = Dstart + (size_t)N * 128 * 4;  // g is largest
    off = (Dearly_end > Dend) ? Dearly_end : Dend;
    if (off > ws_size) return;  // workspace too small: fail cleanly

    int nb1 = (N + 1023) / 1024;

    // ---- partition + CSR build ----
    hipMemsetAsync(degi, 0, (size_t)N * 4, stream);
    hist_pass<<<NPB, 256, 0, stream>>>(dst, E, chunk, shift, blk_hist);
    col_scan<<<NBUCKET, 256, 0, stream>>>(blk_hist, blk_base, bucket_total);
    scan_bucket<<<1, 256, 0, stream>>>(bucket_total, bucket_base);
    scatter_pass<<<NPB, 256, 0, stream>>>(src, dst, E, chunk, shift, bucket_base, blk_base, part);
    count_deg2<<<(E + 255) / 256, 256, 0, stream>>>(part, E, degi);
    scan_blocks<<<nb1, 256, 0, stream>>>(degi, N, row_ptr, partials);
    scan_partials<<<1, 128, 0, stream>>>(partials, nb1);
    finalize_rows<<<(N + 255) / 256, 256, 0, stream>>>(degi, N, row_ptr, partials, cursor, dinv);
    fill_csr2<<<(E + 255) / 256, 256, 0, stream>>>(part, E, dinv, cursor, csr2);

    // ---- compute ----
    // h = x @ W1   (fp16 out)
    sgemm128<0><<<(N + 127) / 128, 256, 0, stream>>>(x, N, W1, nullptr, nullptr, nullptr, h, nullptr);
    // h1 = relu(A @ h + b1)   (fp16 out)
    gather_rows<1, 0><<<(N * 64 + 255) / 256, 256, 0, stream>>>(h, dinv, row_ptr, csr2, b1, h1, N);
    // g = A @ h1              (f32 out)
    gather_rows<0, 1><<<(N * 64 + 255) / 256, 256, 0, stream>>>(h1, dinv, row_ptr, csr2, nullptr, g, N);
    // mu | logstd = g @ [W_mu|W_ls] + [b_mu|b_ls]  -> d_out halves
    sgemm128<1><<<(N + 127) / 128, 256, 0, stream>>>(g, N, Wmu, Wls, bmu, bls, out, out + (size_t)N * 64);
}

// Round 5
// 345.047 us; speedup vs baseline: 1.8393x; 1.0961x over previous
//
#include <hip/hip_runtime.h>
#include <hip/hip_fp16.h>

// ---------------------------------------------------------------------------
// VariationalGCNEncoder on MI355X
//   bucket-partition edges by dst (deterministic 2-pass radix, 1024 buckets)
//   -> count/scan/finalize/fill on partitioned stream (window-local atomics)
//   h   = x @ W1              (SGEMM f32, epilogue stores fp16)
//   h1  = relu(A @ h + b1)    (gather4: 4 edges/load-inst, 16 rows in flight)
//   g   = A @ h1              (gather4 fp16->f32)  [shared by mu & logstd]
//   mu | logstd = g @ [W_mu|W_ls] + bias           (SGEMM f32, split epilogue)
// ---------------------------------------------------------------------------

#define NBUCKET 1024
#define NPB 512  // partition blocks; chunk = ceil(E/NPB)

// ---- partition pass 1: per-block bucket histogram --------------------------
__global__ __launch_bounds__(256) void hist_pass(const int* __restrict__ dst, int E,
                                                 int chunk, int shift,
                                                 int* __restrict__ blk_hist) {
    __shared__ int hist[NBUCKET];
    for (int i = threadIdx.x; i < NBUCKET; i += 256) hist[i] = 0;
    __syncthreads();
    int b = blockIdx.x;
    int beg = b * chunk;
    int end = beg + chunk; if (end > E) end = E;
    for (int i = beg + threadIdx.x; i < end; i += 256)
        atomicAdd(&hist[dst[i] >> shift], 1);
    __syncthreads();
    for (int i = threadIdx.x; i < NBUCKET; i += 256)
        blk_hist[(size_t)b * NBUCKET + i] = hist[i];
}

// ---- partition pass 2: per-bucket column scan (one block per bucket) -------
__global__ __launch_bounds__(256) void col_scan(const int* __restrict__ blk_hist,
                                                int* __restrict__ blk_base,
                                                int* __restrict__ bucket_total) {
    __shared__ int sh[256];
    int q = blockIdx.x, t = threadIdx.x;
    int v0 = blk_hist[(size_t)(2 * t) * NBUCKET + q];
    int v1 = blk_hist[(size_t)(2 * t + 1) * NBUCKET + q];
    int s = v0 + v1;
    sh[t] = s;
    __syncthreads();
    for (int off = 1; off < 256; off <<= 1) {
        int x = (t >= off) ? sh[t - off] : 0;
        __syncthreads();
        sh[t] += x;
        __syncthreads();
    }
    int pre = sh[t] - s;
    blk_base[(size_t)(2 * t) * NBUCKET + q] = pre;
    blk_base[(size_t)(2 * t + 1) * NBUCKET + q] = pre + v0;
    if (t == 255) bucket_total[q] = sh[255];
}

// ---- exclusive scan of 1024 bucket totals (single block) -------------------
__global__ __launch_bounds__(256) void scan_bucket(const int* __restrict__ total,
                                                   int* __restrict__ base) {
    __shared__ int sh[256];
    int t = threadIdx.x;
    int idx0 = t * 4;
    int v[4];
#pragma unroll
    for (int k = 0; k < 4; ++k) v[k] = total[idx0 + k];
    int s = v[0] + v[1] + v[2] + v[3];
    sh[t] = s;
    __syncthreads();
    for (int off = 1; off < 256; off <<= 1) {
        int x = (t >= off) ? sh[t - off] : 0;
        __syncthreads();
        sh[t] += x;
        __syncthreads();
    }
    int run = sh[t] - s;
#pragma unroll
    for (int k = 0; k < 4; ++k) {
        base[idx0 + k] = run;
        run += v[k];
    }
}

// ---- partition pass 3: scatter (dst,src) pairs into bucket-ordered part[] --
__global__ __launch_bounds__(256) void scatter_pass(const int* __restrict__ src,
                                                    const int* __restrict__ dst, int E,
                                                    int chunk, int shift,
                                                    const int* __restrict__ bucket_base,
                                                    const int* __restrict__ blk_base,
                                                    long long* __restrict__ part) {
    __shared__ int cur[NBUCKET];
    int b = blockIdx.x;
    for (int i = threadIdx.x; i < NBUCKET; i += 256)
        cur[i] = bucket_base[i] + blk_base[(size_t)b * NBUCKET + i];
    __syncthreads();
    int beg = b * chunk;
    int end = beg + chunk; if (end > E) end = E;
    for (int i = beg + threadIdx.x; i < end; i += 256) {
        int d = dst[i], s = src[i];
        int q = d >> shift;
        int p = atomicAdd(&cur[q], 1);
        part[p] = ((long long)(unsigned)d << 32) | (unsigned)s;
    }
}

// ---- degree count over the partitioned stream (window-local atomics) -------
__global__ void count_deg2(const long long* __restrict__ part, int E,
                           int* __restrict__ degi) {
    int i = blockIdx.x * blockDim.x + threadIdx.x;
    if (i < E) {
        int d = (int)(unsigned)((unsigned long long)part[i] >> 32);
        atomicAdd(&degi[d], 1);
    }
}

// 256 threads, 1024 elements per block. Chunk-local inclusive scan into
// row_ptr[ix+1], block totals into partials[].
__global__ __launch_bounds__(256) void scan_blocks(const int* __restrict__ degi, int n,
                                                   int* __restrict__ row_ptr,
                                                   int* __restrict__ partials) {
    __shared__ int sh[256];
    int t = threadIdx.x;
    int base = blockIdx.x * 1024;
    int idx0 = base + t * 4;
    int v[4];
#pragma unroll
    for (int i = 0; i < 4; ++i) {
        int ix = idx0 + i;
        v[i] = (ix < n) ? degi[ix] : 0;
    }
    int s = v[0] + v[1] + v[2] + v[3];
    sh[t] = s;
    __syncthreads();
    for (int off = 1; off < 256; off <<= 1) {
        int x = (t >= off) ? sh[t - off] : 0;
        __syncthreads();
        sh[t] += x;
        __syncthreads();
    }
    int run = sh[t] - s;
#pragma unroll
    for (int i = 0; i < 4; ++i) {
        int ix = idx0 + i;
        run += v[i];
        if (ix < n) row_ptr[ix + 1] = run;
    }
    if (t == 255) partials[blockIdx.x] = sh[255];
}

// nb <= 128. Exclusive scan of block totals, in place.
__global__ void scan_partials(int* __restrict__ partials, int nb) {
    __shared__ int sh[128];
    int t = threadIdx.x;
    int v = (t < nb) ? partials[t] : 0;
    sh[t] = v;
    __syncthreads();
    for (int off = 1; off < 128; off <<= 1) {
        int x = (t >= off) ? sh[t - off] : 0;
        __syncthreads();
        sh[t] += x;
        __syncthreads();
    }
    if (t < nb) partials[t] = sh[t] - v;
}

__global__ void finalize_rows(const int* __restrict__ degi, int n,
                              int* __restrict__ row_ptr, const int* __restrict__ partials,
                              int* __restrict__ cursor, float* __restrict__ dinv) {
    int i = blockIdx.x * blockDim.x + threadIdx.x;
    if (i == 0) row_ptr[0] = 0;
    if (i < n) {
        int p = partials[i >> 10];
        int rp1 = row_ptr[i + 1] + p;
        row_ptr[i + 1] = rp1;
        cursor[i] = rp1 - degi[i];                 // == final row_ptr[i]
        dinv[i] = rsqrtf((float)(degi[i] + 1));    // +1: self-loop
    }
}

// ---- CSR fill from partitioned pairs: window-local cursor + csr2 writes ----
__global__ void fill_csr2(const long long* __restrict__ part, int E,
                          const float* __restrict__ dinv,
                          int* __restrict__ cursor, long long* __restrict__ csr2) {
    int i = blockIdx.x * blockDim.x + threadIdx.x;
    if (i < E) {
        long long pr = part[i];
        int d = (int)(unsigned)((unsigned long long)pr >> 32);
        int s = (int)(unsigned)(pr & 0xffffffffLL);
        int p = atomicAdd(&cursor[d], 1);
        float w = dinv[s] * dinv[d];
        long long rec = (long long)(unsigned)s |
                        ((long long)(unsigned)__float_as_uint(w) << 32);
        csr2[p] = rec;
    }
}

// One wave per destination node. 4 groups of 16 lanes; group g handles edge
// slot g of each quad, lane covers channels (lane&15)*8..+7 as one dwordx4
// (8 fp16). 4-quad unroll -> 16 rows in flight per wave from 4 load insts.
// f32 accumulate; butterfly reduce over groups at the end; lanes 0-15 store
// 16B each. Self-loop folded into group 0's init.
// FUSE=1: out = relu(acc + bias). OUT_F32: store f32 row, else fp16 row.
template <int FUSE, int OUT_F32>
__global__ __launch_bounds__(256) void gather_rows4(const __half* __restrict__ h,
                                                    const float* __restrict__ dinv,
                                                    const int* __restrict__ row_ptr,
                                                    const long long* __restrict__ csr2,
                                                    const float* __restrict__ bias,
                                                    void* __restrict__ out, int n) {
    int wid = (blockIdx.x * 256 + threadIdx.x) >> 6;
    int lane = threadIdx.x & 63;
    if (wid >= n) return;
    int grp = lane >> 4;   // edge slot within quad
    int cs  = lane & 15;   // channel-slice: 8 halves at cs*8
    float dv = dinv[wid];
    int beg = row_ptr[wid];
    int end = row_ptr[wid + 1];

    float acc[8];
    {
        float4 raw = *(const float4*)(h + (size_t)wid * 128 + cs * 8);
        const __half2* hp = (const __half2*)&raw;
        float sw = (grp == 0) ? dv * dv : 0.0f;  // self-loop only in group 0
#pragma unroll
        for (int q = 0; q < 4; ++q) {
            float2 f = __half22float2(hp[q]);
            acc[2 * q]     = sw * f.x;
            acc[2 * q + 1] = sw * f.y;
        }
    }

#pragma unroll 1
    for (int j = beg; j < end; j += 16) {
        long long e[4];
#pragma unroll
        for (int u = 0; u < 4; ++u) {
            int idx = j + u * 4 + grp;
            e[u] = csr2[idx < end ? idx : beg];
        }
        float4 raw[4];
        float w[4];
#pragma unroll
        for (int u = 0; u < 4; ++u) {
            int s = (int)(unsigned)(e[u] & 0xffffffffLL);
            w[u] = __uint_as_float((unsigned)((unsigned long long)e[u] >> 32));
            if (j + u * 4 + grp >= end) w[u] = 0.0f;
            raw[u] = *(const float4*)(h + (size_t)s * 128 + cs * 8);
        }
#pragma unroll
        for (int u = 0; u < 4; ++u) {
            const __half2* hp = (const __half2*)&raw[u];
#pragma unroll
            for (int q = 0; q < 4; ++q) {
                float2 f = __half22float2(hp[q]);
                acc[2 * q]     = fmaf(w[u], f.x, acc[2 * q]);
                acc[2 * q + 1] = fmaf(w[u], f.y, acc[2 * q + 1]);
            }
        }
    }

    // reduce the 4 groups (lanes xor 16, 32)
#pragma unroll
    for (int q = 0; q < 8; ++q) {
        acc[q] += __shfl_xor(acc[q], 16, 64);
        acc[q] += __shfl_xor(acc[q], 32, 64);
    }

    if (FUSE) {
        const float4* bp = (const float4*)(bias + cs * 8);
        float4 b0 = bp[0], b1 = bp[1];
        acc[0] = fmaxf(acc[0] + b0.x, 0.0f);
        acc[1] = fmaxf(acc[1] + b0.y, 0.0f);
        acc[2] = fmaxf(acc[2] + b0.z, 0.0f);
        acc[3] = fmaxf(acc[3] + b0.w, 0.0f);
        acc[4] = fmaxf(acc[4] + b1.x, 0.0f);
        acc[5] = fmaxf(acc[5] + b1.y, 0.0f);
        acc[6] = fmaxf(acc[6] + b1.z, 0.0f);
        acc[7] = fmaxf(acc[7] + b1.w, 0.0f);
    }

    if (lane < 16) {
        if (OUT_F32) {
            float4* op = (float4*)((float*)out + (size_t)wid * 128 + cs * 8);
            op[0] = make_float4(acc[0], acc[1], acc[2], acc[3]);
            op[1] = make_float4(acc[4], acc[5], acc[6], acc[7]);
        } else {
            union { __half2 h2[4]; float4 f4; } u;
            u.h2[0] = __floats2half2_rn(acc[0], acc[1]);
            u.h2[1] = __floats2half2_rn(acc[2], acc[3]);
            u.h2[2] = __floats2half2_rn(acc[4], acc[5]);
            u.h2[3] = __floats2half2_rn(acc[6], acc[7]);
            *(float4*)((__half*)out + (size_t)wid * 128 + cs * 8) = u.f4;
        }
    }
}

// C[M,128] = A[M,128] @ B[128,128]; 256 thr, BM=BN=128, BK=32, 8x8 micro-tile.
// MODE 0: B = B0 (128 wide), write C0 as fp16 [M,128].
// MODE 1: B cols 0-63 from B0(=W_mu), 64-127 from B1(=W_ls); epilogue adds
//         bias and writes f32 halves to C0 (mu) and C1 (logstd), each [M,64].
template <int MODE>
__global__ __launch_bounds__(256) void sgemm128(const float* __restrict__ A, int M,
                                                const float* __restrict__ B0,
                                                const float* __restrict__ B1,
                                                const float* __restrict__ bias0,
                                                const float* __restrict__ bias1,
                                                void* __restrict__ C0v,
                                                float* __restrict__ C1) {
    __shared__ float As[32][132];
    __shared__ float Bs[32][128];
    int tid = threadIdx.x;
    int row0 = blockIdx.x * 128;
    int tx = tid & 15, ty = tid >> 4;
    float acc[8][8] = {};
    for (int k0 = 0; k0 < 128; k0 += 32) {
#pragma unroll
        for (int i = 0; i < 4; ++i) {
            int idx = tid + i * 256;       // 0..1023
            int r = idx >> 3;              // 0..127
            int c4 = (idx & 7) << 2;       // 0..28
            int grow = row0 + r;
            float4 v = make_float4(0.f, 0.f, 0.f, 0.f);
            if (grow < M) v = *(const float4*)(A + (size_t)grow * 128 + k0 + c4);
            As[c4 + 0][r] = v.x;
            As[c4 + 1][r] = v.y;
            As[c4 + 2][r] = v.z;
            As[c4 + 3][r] = v.w;
        }
#pragma unroll
        for (int i = 0; i < 4; ++i) {
            int idx = tid + i * 256;
            int r = idx >> 5;              // 0..31
            int c4 = (idx & 31) << 2;      // 0..124
            const float* bp;
            if (MODE == 0) {
                bp = B0 + (size_t)(k0 + r) * 128 + c4;
            } else {
                bp = (c4 < 64) ? (B0 + (size_t)(k0 + r) * 64 + c4)
                               : (B1 + (size_t)(k0 + r) * 64 + (c4 - 64));
            }
            *(float4*)&Bs[r][c4] = *(const float4*)bp;
        }
        __syncthreads();
#pragma unroll
        for (int k = 0; k < 32; ++k) {
            float a[8], b[8];
            *(float4*)&a[0] = *(const float4*)&As[k][ty * 4];
            *(float4*)&a[4] = *(const float4*)&As[k][64 + ty * 4];
            *(float4*)&b[0] = *(const float4*)&Bs[k][tx * 4];
            *(float4*)&b[4] = *(const float4*)&Bs[k][64 + tx * 4];
#pragma unroll
            for (int i = 0; i < 8; ++i)
#pragma unroll
                for (int j = 0; j < 8; ++j) acc[i][j] = fmaf(a[i], b[j], acc[i][j]);
        }
        __syncthreads();
    }
#pragma unroll
    for (int ig = 0; ig < 2; ++ig) {
#pragma unroll
        for (int ii = 0; ii < 4; ++ii) {
            int i = ig * 4 + ii;
            int grow = row0 + ig * 64 + ty * 4 + ii;
            if (grow >= M) continue;
#pragma unroll
            for (int jg = 0; jg < 2; ++jg) {
                float4 v = make_float4(acc[i][jg * 4 + 0], acc[i][jg * 4 + 1],
                                       acc[i][jg * 4 + 2], acc[i][jg * 4 + 3]);
                if (MODE == 0) {
                    __half* cp = (__half*)C0v + (size_t)grow * 128 + jg * 64 + tx * 4;
                    *(__half2*)(cp + 0) = __floats2half2_rn(v.x, v.y);
                    *(__half2*)(cp + 2) = __floats2half2_rn(v.z, v.w);
                } else {
                    int c = tx * 4;
                    const float* bs = (jg == 0) ? bias0 : bias1;
                    v.x += bs[c + 0];
                    v.y += bs[c + 1];
                    v.z += bs[c + 2];
                    v.w += bs[c + 3];
                    float* cp = ((jg == 0) ? (float*)C0v : C1) + (size_t)grow * 64 + c;
                    *(float4*)cp = v;
                }
            }
        }
    }
}

extern "C" void kernel_launch(void* const* d_in, const int* in_sizes, int n_in,
                              void* d_out, int out_size, void* d_ws, size_t ws_size,
                              hipStream_t stream) {
    const float* x   = (const float*)d_in[0];
    const int*  eidx = (const int*)d_in[1];
    const float* W1  = (const float*)d_in[2];
    const float* b1  = (const float*)d_in[3];
    const float* Wmu = (const float*)d_in[4];
    const float* bmu = (const float*)d_in[5];
    const float* Wls = (const float*)d_in[6];
    const float* bls = (const float*)d_in[7];
    float* out = (float*)d_out;

    const int N = in_sizes[0] / 128;  // 100000
    const int E = in_sizes[1] / 2;    // 1600000
    const int* src = eidx;
    const int* dst = eidx + E;

    int shift = 0;
    while (((N - 1) >> shift) >= NBUCKET) ++shift;  // N=100000 -> 7
    int chunk = (E + NPB - 1) / NPB;

    char* w = (char*)d_ws;
    size_t off = 0;
    auto alloc = [&](size_t bytes) {
        void* p = w + off;
        off += (bytes + 255) & ~(size_t)255;
        return p;
    };
    // persistent region
    int*       row_ptr      = (int*)alloc((size_t)(N + 1) * 4);
    int*       cursor       = (int*)alloc((size_t)N * 4);
    float*     dinv         = (float*)alloc((size_t)N * 4);
    int*       partials     = (int*)alloc(512);
    int*       bucket_total = (int*)alloc(NBUCKET * 4);
    int*       bucket_base  = (int*)alloc(NBUCKET * 4);
    long long* csr2         = (long long*)alloc((size_t)E * 8);
    __half*    h1           = (__half*)alloc((size_t)N * 128 * 2);
    // region D: early partition buffers, then h (fp16), then g (f32) — all
    // lifetimes disjoint (partition dead before sgemm1; h dead before gather2)
    size_t Dstart = off;
    int*       degi     = (int*)alloc((size_t)N * 4);
    int*       blk_hist = (int*)alloc((size_t)NPB * NBUCKET * 4);
    int*       blk_base = (int*)alloc((size_t)NPB * NBUCKET * 4);
    long long* part     = (long long*)alloc((size_t)E * 8);
    size_t Dearly_end = off;
    __half* h = (__half*)(w + Dstart);
    float*  g = (float*)(w + Dstart);
    size_t Dend = Dstart + (size_t)N * 128 * 4;  // g is largest
    off = (Dearly_end > Dend) ? Dearly_end : Dend;
    if (off > ws_size) return;  // workspace too small: fail cleanly

    int nb1 = (N + 1023) / 1024;

    // ---- partition + CSR build ----
    hipMemsetAsync(degi, 0, (size_t)N * 4, stream);
    hist_pass<<<NPB, 256, 0, stream>>>(dst, E, chunk, shift, blk_hist);
    col_scan<<<NBUCKET, 256, 0, stream>>>(blk_hist, blk_base, bucket_total);
    scan_bucket<<<1, 256, 0, stream>>>(bucket_total, bucket_base);
    scatter_pass<<<NPB, 256, 0, stream>>>(src, dst, E, chunk, shift, bucket_base, blk_base, part);
    count_deg2<<<(E + 255) / 256, 256, 0, stream>>>(part, E, degi);
    scan_blocks<<<nb1, 256, 0, stream>>>(degi, N, row_ptr, partials);
    scan_partials<<<1, 128, 0, stream>>>(partials, nb1);
    finalize_rows<<<(N + 255) / 256, 256, 0, stream>>>(degi, N, row_ptr, partials, cursor, dinv);
    fill_csr2<<<(E + 255) / 256, 256, 0, stream>>>(part, E, dinv, cursor, csr2);

    // ---- compute ----
    // h = x @ W1   (fp16 out)
    sgemm128<0><<<(N + 127) / 128, 256, 0, stream>>>(x, N, W1, nullptr, nullptr, nullptr, h, nullptr);
    // h1 = relu(A @ h + b1)   (fp16 out)
    gather_rows4<1, 0><<<(N * 64 + 255) / 256, 256, 0, stream>>>(h, dinv, row_ptr, csr2, b1, h1, N);
    // g = A @ h1              (f32 out)
    gather_rows4<0, 1><<<(N * 64 + 255) / 256, 256, 0, stream>>>(h1, dinv, row_ptr, csr2, nullptr, g, N);
    // mu | logstd = g @ [W_mu|W_ls] + [b_mu|b_ls]  -> d_out halves
    sgemm128<1><<<(N + 127) / 128, 256, 0, stream>>>(g, N, Wmu, Wls, bmu, bls, out, out + (size_t)N * 64);
}

// Round 6
// 292.955 us; speedup vs baseline: 2.1664x; 1.1778x over previous
//
#include <hip/hip_runtime.h>
#include <hip/hip_fp16.h>

// ---------------------------------------------------------------------------
// VariationalGCNEncoder on MI355X
//   radix partition by dst (1024 buckets = 128-node windows)
//   bucket_count: per-bucket LDS count -> degi, dinv, padded totals
//   scan_bucket:  1024-entry exclusive scan (reused twice)
//   bucket_fill:  per-bucket row_ptr + scatter (s,w) into padded csr2,
//                 LDS cursors only, pair-padded to equal 16-slot lengths
//   h  = x @ W1                (SGEMM f32->fp16)
//   h1 = relu(A @ h + b1)      (gather_pair: 2 nodes/wave, 32 rows in flight,
//   g  = A @ h1                 mask-free padded inner loop, fp16 out)
//   mu|logstd = g @ [W_mu|W_ls] + bias  (SGEMM fp16-A f32-out split epilogue)
// ---------------------------------------------------------------------------

#define NBUCKET 1024
#define NPB 512  // partition blocks; chunk = ceil(E/NPB)

// ---- partition pass 1: per-block bucket histogram --------------------------
__global__ __launch_bounds__(256) void hist_pass(const int* __restrict__ dst, int E,
                                                 int chunk, int shift,
                                                 int* __restrict__ blk_hist) {
    __shared__ int hist[NBUCKET];
    for (int i = threadIdx.x; i < NBUCKET; i += 256) hist[i] = 0;
    __syncthreads();
    int b = blockIdx.x;
    int beg = b * chunk;
    int end = beg + chunk; if (end > E) end = E;
    for (int i = beg + threadIdx.x; i < end; i += 256)
        atomicAdd(&hist[dst[i] >> shift], 1);
    __syncthreads();
    for (int i = threadIdx.x; i < NBUCKET; i += 256)
        blk_hist[(size_t)b * NBUCKET + i] = hist[i];
}

// ---- partition pass 2: per-bucket column scan (one block per bucket) -------
__global__ __launch_bounds__(256) void col_scan(const int* __restrict__ blk_hist,
                                                int* __restrict__ blk_base,
                                                int* __restrict__ bucket_total) {
    __shared__ int sh[256];
    int q = blockIdx.x, t = threadIdx.x;
    int v0 = blk_hist[(size_t)(2 * t) * NBUCKET + q];
    int v1 = blk_hist[(size_t)(2 * t + 1) * NBUCKET + q];
    int s = v0 + v1;
    sh[t] = s;
    __syncthreads();
    for (int off = 1; off < 256; off <<= 1) {
        int x = (t >= off) ? sh[t - off] : 0;
        __syncthreads();
        sh[t] += x;
        __syncthreads();
    }
    int pre = sh[t] - s;
    blk_base[(size_t)(2 * t) * NBUCKET + q] = pre;
    blk_base[(size_t)(2 * t + 1) * NBUCKET + q] = pre + v0;
    if (t == 255) bucket_total[q] = sh[255];
}

// ---- exclusive scan of 1024 values (single block), used twice --------------
__global__ __launch_bounds__(256) void scan_bucket(const int* __restrict__ total,
                                                   int* __restrict__ base) {
    __shared__ int sh[256];
    int t = threadIdx.x;
    int idx0 = t * 4;
    int v[4];
#pragma unroll
    for (int k = 0; k < 4; ++k) v[k] = total[idx0 + k];
    int s = v[0] + v[1] + v[2] + v[3];
    sh[t] = s;
    __syncthreads();
    for (int off = 1; off < 256; off <<= 1) {
        int x = (t >= off) ? sh[t - off] : 0;
        __syncthreads();
        sh[t] += x;
        __syncthreads();
    }
    int run = sh[t] - s;
#pragma unroll
    for (int k = 0; k < 4; ++k) {
        base[idx0 + k] = run;
        run += v[k];
    }
}

// ---- partition pass 3: scatter (dst,src) pairs into bucket-ordered part[] --
__global__ __launch_bounds__(256) void scatter_pass(const int* __restrict__ src,
                                                    const int* __restrict__ dst, int E,
                                                    int chunk, int shift,
                                                    const int* __restrict__ bucket_base,
                                                    const int* __restrict__ blk_base,
                                                    long long* __restrict__ part) {
    __shared__ int cur[NBUCKET];
    int b = blockIdx.x;
    for (int i = threadIdx.x; i < NBUCKET; i += 256)
        cur[i] = bucket_base[i] + blk_base[(size_t)b * NBUCKET + i];
    __syncthreads();
    int beg = b * chunk;
    int end = beg + chunk; if (end > E) end = E;
    for (int i = beg + threadIdx.x; i < end; i += 256) {
        int d = dst[i], s = src[i];
        int q = d >> shift;
        int p = atomicAdd(&cur[q], 1);
        part[p] = ((long long)(unsigned)d << 32) | (unsigned)s;
    }
}

// ---- bucket_count: LDS count -> degi, dinv, padded bucket total -------------
// Padding: node pair (2i,2i+1) both padded to 16*max(ceil(dA/16),ceil(dB/16)).
__global__ __launch_bounds__(256) void bucket_count(const long long* __restrict__ part,
                                                    const int* __restrict__ bucket_base,
                                                    const int* __restrict__ bucket_total,
                                                    int N, int shift,
                                                    int* __restrict__ degi,
                                                    float* __restrict__ dinv,
                                                    int* __restrict__ padded_total) {
    __shared__ int cnt[128];
    __shared__ int sh[128];
    int b = blockIdx.x, t = threadIdx.x;
    if (t < 128) cnt[t] = 0;
    __syncthreads();
    int node0 = b << shift;
    int beg = bucket_base[b];
    int end = beg + bucket_total[b];
    for (int i = beg + t; i < end; i += 256) {
        int d = (int)((unsigned long long)part[i] >> 32);
        atomicAdd(&cnt[d - node0], 1);
    }
    __syncthreads();
    if (t < 128) {
        int node = node0 + t;
        int c = (node < N) ? cnt[t] : 0;
        if (node < N) {
            degi[node] = c;
            dinv[node] = rsqrtf((float)(c + 1));
        }
        sh[t] = c;  // stash real count for pair-padding below
    }
    __syncthreads();
    int padded = 0;
    if (t < 128) {
        int node = node0 + t;
        if (node < N) {
            int mine = (sh[t] + 15) >> 4;
            int partner_idx = t ^ 1;
            int pnode = node0 + partner_idx;
            int theirs = (pnode < N) ? ((sh[partner_idx] + 15) >> 4) : 0;
            int L = mine > theirs ? mine : theirs;
            padded = L << 4;
        }
    }
    __syncthreads();
    if (t < 128) sh[t] = padded;
    __syncthreads();
    for (int off = 64; off >= 1; off >>= 1) {
        if (t < off) sh[t] += sh[t + off];
        __syncthreads();
    }
    if (t == 0) padded_total[b] = sh[0];
}

// ---- bucket_fill: row_ptr + weighted scatter into padded csr2 ---------------
__global__ __launch_bounds__(256) void bucket_fill(const long long* __restrict__ part,
                                                   const int* __restrict__ bucket_base,
                                                   const int* __restrict__ bucket_total,
                                                   const int* __restrict__ padded_base,
                                                   const int* __restrict__ degi,
                                                   const float* __restrict__ dinv,
                                                   int N, int shift,
                                                   int* __restrict__ row_ptr,
                                                   long long* __restrict__ csr2) {
    __shared__ int sh[128];
    __shared__ int pexcl[128];
    __shared__ int padarr[128];
    __shared__ int cur[128];
    __shared__ float dvl[128];
    int b = blockIdx.x, t = threadIdx.x;
    int node0 = b << shift;
    int pbase = padded_base[b];

    int deg = 0;
    if (t < 128) {
        int node = node0 + t;
        deg = (node < N) ? degi[node] : 0;
        dvl[t] = (node < N) ? dinv[node] : 0.0f;
        sh[t] = deg;  // real counts, for pair padding
    }
    __syncthreads();
    int padded = 0;
    if (t < 128) {
        int node = node0 + t;
        if (node < N) {
            int mine = (sh[t] + 15) >> 4;
            int pi = t ^ 1;
            int pnode = node0 + pi;
            int theirs = (pnode < N) ? ((sh[pi] + 15) >> 4) : 0;
            int L = mine > theirs ? mine : theirs;
            padded = L << 4;
        }
        padarr[t] = padded;
    }
    __syncthreads();
    if (t < 128) sh[t] = padded;
    __syncthreads();
    for (int off = 1; off < 128; off <<= 1) {
        int x = 0;
        if (t < 128 && t >= off) x = sh[t - off];
        __syncthreads();
        if (t < 128) sh[t] += x;
        __syncthreads();
    }
    if (t < 128) {
        int excl = sh[t] - padarr[t];
        pexcl[t] = excl;
        cur[t] = pbase + excl;
        int node = node0 + t;
        if (node < N) row_ptr[node] = pbase + excl;
    }
    __syncthreads();
    if (t == 0) {
        int boundary = node0 + 128;
        if (boundary > N) boundary = N;
        row_ptr[boundary] = pbase + sh[127];  // benign overlap with next bucket
    }
    // scatter edges with weights (LDS cursors; dinv[s] is L2-resident 400KB)
    int ebeg = bucket_base[b];
    int eend = ebeg + bucket_total[b];
    for (int i = ebeg + t; i < eend; i += 256) {
        long long pr = part[i];
        int d = (int)((unsigned long long)pr >> 32);
        int s = (int)(unsigned)(pr & 0xffffffffLL);
        int dl = d - node0;
        int p = atomicAdd(&cur[dl], 1);
        float w = dinv[s] * dvl[dl];
        csr2[p] = (long long)(unsigned)s |
                  ((long long)(unsigned)__float_as_uint(w) << 32);
    }
    __syncthreads();
    // pads: (s=node, w=0) -> gather adds 0 * h[node] (always in-bounds)
    if (t < 128) {
        int node = node0 + t;
        if (node < N) {
            int endp = pbase + pexcl[t] + padarr[t];
            long long rec = (long long)(unsigned)node;  // hi bits 0 -> w=0.0f
            for (int p = cur[t]; p < endp; ++p) csr2[p] = rec;
        }
    }
}

// ---- gather: 2 nodes per wave, mask-free padded inner loop ------------------
// halves: lanes 0-31 node 2w, lanes 32-63 node 2w+1 (pair-padded equal length)
// per half: 2 edge-slot groups x 16 channel-lanes; U=8 -> 16 slots per iter
// per half, 32 rows in flight per wave. f32 accumulate; xor-16 reduce; fp16 out.
template <int FUSE>
__global__ __launch_bounds__(256) void gather_pair(const __half* __restrict__ h,
                                                   const float* __restrict__ dinv,
                                                   const int* __restrict__ row_ptr,
                                                   const long long* __restrict__ csr2,
                                                   const float* __restrict__ bias,
                                                   __half* __restrict__ out, int n) {
    int wv = (blockIdx.x * 256 + threadIdx.x) >> 6;
    int lane = threadIdx.x & 63;
    int nodeA = wv * 2;
    if (nodeA >= n) return;
    int half = lane >> 5;                 // 0: nodeA, 1: nodeB
    int grp2 = (lane >> 4) & 1;           // edge-slot parity within half
    int cs = lane & 15;                   // channel slice: 8 halves at cs*8
    int bvalid = (nodeA + 1) < n;
    int wid = nodeA + (half & bvalid);    // invalid B mirrors A (discarded)
    float dv = dinv[wid];
    int beg = row_ptr[wid];
    int end = row_ptr[wid + 1];

    float acc[8];
    {
        float4 raw = *(const float4*)(h + (size_t)wid * 128 + cs * 8);
        const __half2* hp = (const __half2*)&raw;
        float sw = (grp2 == 0) ? dv * dv : 0.0f;  // self-loop in slot-group 0
#pragma unroll
        for (int q = 0; q < 4; ++q) {
            float2 f = __half22float2(hp[q]);
            acc[2 * q]     = sw * f.x;
            acc[2 * q + 1] = sw * f.y;
        }
    }

#pragma unroll 1
    for (int j = beg; j < end; j += 16) {
        long long e[8];
#pragma unroll
        for (int u = 0; u < 8; ++u) e[u] = csr2[j + u * 2 + grp2];
        float4 raw[8];
        float w[8];
#pragma unroll
        for (int u = 0; u < 8; ++u) {
            int s = (int)(unsigned)(e[u] & 0xffffffffLL);
            w[u] = __uint_as_float((unsigned)((unsigned long long)e[u] >> 32));
            raw[u] = *(const float4*)(h + (size_t)s * 128 + cs * 8);
        }
#pragma unroll
        for (int u = 0; u < 8; ++u) {
            const __half2* hp = (const __half2*)&raw[u];
#pragma unroll
            for (int q = 0; q < 4; ++q) {
                float2 f = __half22float2(hp[q]);
                acc[2 * q]     = fmaf(w[u], f.x, acc[2 * q]);
                acc[2 * q + 1] = fmaf(w[u], f.y, acc[2 * q + 1]);
            }
        }
    }

    // combine the two slot-groups of each half (lane xor 16)
#pragma unroll
    for (int q = 0; q < 8; ++q) acc[q] += __shfl_xor(acc[q], 16, 64);

    if (FUSE) {
        const float4* bp = (const float4*)(bias + cs * 8);
        float4 b0 = bp[0], b1 = bp[1];
        acc[0] = fmaxf(acc[0] + b0.x, 0.0f);
        acc[1] = fmaxf(acc[1] + b0.y, 0.0f);
        acc[2] = fmaxf(acc[2] + b0.z, 0.0f);
        acc[3] = fmaxf(acc[3] + b0.w, 0.0f);
        acc[4] = fmaxf(acc[4] + b1.x, 0.0f);
        acc[5] = fmaxf(acc[5] + b1.y, 0.0f);
        acc[6] = fmaxf(acc[6] + b1.z, 0.0f);
        acc[7] = fmaxf(acc[7] + b1.w, 0.0f);
    }

    if ((lane & 31) < 16 && (half == 0 || bvalid)) {
        union { __half2 h2[4]; float4 f4; } u;
        u.h2[0] = __floats2half2_rn(acc[0], acc[1]);
        u.h2[1] = __floats2half2_rn(acc[2], acc[3]);
        u.h2[2] = __floats2half2_rn(acc[4], acc[5]);
        u.h2[3] = __floats2half2_rn(acc[6], acc[7]);
        *(float4*)(out + (size_t)wid * 128 + cs * 8) = u.f4;
    }
}

// C[M,128] = A[M,128] @ B[128,128]; 256 thr, BM=BN=128, BK=32, 8x8 micro-tile.
// AH=1: A is fp16 (converted to f32 in the LDS staging load).
// MODE 0: B = B0 (128 wide), write C0 as fp16 [M,128].
// MODE 1: B cols 0-63 from B0(=W_mu), 64-127 from B1(=W_ls); epilogue adds
//         bias and writes f32 halves to C0 (mu) and C1 (logstd), each [M,64].
template <int MODE, int AH>
__global__ __launch_bounds__(256) void sgemm128(const void* __restrict__ Av, int M,
                                                const float* __restrict__ B0,
                                                const float* __restrict__ B1,
                                                const float* __restrict__ bias0,
                                                const float* __restrict__ bias1,
                                                void* __restrict__ C0v,
                                                float* __restrict__ C1) {
    __shared__ float As[32][132];
    __shared__ float Bs[32][128];
    int tid = threadIdx.x;
    int row0 = blockIdx.x * 128;
    int tx = tid & 15, ty = tid >> 4;
    float acc[8][8] = {};
    for (int k0 = 0; k0 < 128; k0 += 32) {
        if (AH) {
            const __half* A = (const __half*)Av;
#pragma unroll
            for (int i = 0; i < 2; ++i) {
                int idx = tid + i * 256;       // 0..511
                int r = idx >> 2;              // 0..127
                int c8 = (idx & 3) << 3;       // 0..24
                int grow = row0 + r;
                float4 rv = make_float4(0.f, 0.f, 0.f, 0.f);
                if (grow < M) rv = *(const float4*)(A + (size_t)grow * 128 + k0 + c8);
                const __half2* hp = (const __half2*)&rv;
#pragma unroll
                for (int q = 0; q < 4; ++q) {
                    float2 f = __half22float2(hp[q]);
                    As[c8 + 2 * q][r]     = f.x;
                    As[c8 + 2 * q + 1][r] = f.y;
                }
            }
        } else {
            const float* A = (const float*)Av;
#pragma unroll
            for (int i = 0; i < 4; ++i) {
                int idx = tid + i * 256;       // 0..1023
                int r = idx >> 3;              // 0..127
                int c4 = (idx & 7) << 2;       // 0..28
                int grow = row0 + r;
                float4 v = make_float4(0.f, 0.f, 0.f, 0.f);
                if (grow < M) v = *(const float4*)(A + (size_t)grow * 128 + k0 + c4);
                As[c4 + 0][r] = v.x;
                As[c4 + 1][r] = v.y;
                As[c4 + 2][r] = v.z;
                As[c4 + 3][r] = v.w;
            }
        }
#pragma unroll
        for (int i = 0; i < 4; ++i) {
            int idx = tid + i * 256;
            int r = idx >> 5;              // 0..31
            int c4 = (idx & 31) << 2;      // 0..124
            const float* bp;
            if (MODE == 0) {
                bp = B0 + (size_t)(k0 + r) * 128 + c4;
            } else {
                bp = (c4 < 64) ? (B0 + (size_t)(k0 + r) * 64 + c4)
                               : (B1 + (size_t)(k0 + r) * 64 + (c4 - 64));
            }
            *(float4*)&Bs[r][c4] = *(const float4*)bp;
        }
        __syncthreads();
#pragma unroll
        for (int k = 0; k < 32; ++k) {
            float a[8], b[8];
            *(float4*)&a[0] = *(const float4*)&As[k][ty * 4];
            *(float4*)&a[4] = *(const float4*)&As[k][64 + ty * 4];
            *(float4*)&b[0] = *(const float4*)&Bs[k][tx * 4];
            *(float4*)&b[4] = *(const float4*)&Bs[k][64 + tx * 4];
#pragma unroll
            for (int i = 0; i < 8; ++i)
#pragma unroll
                for (int j = 0; j < 8; ++j) acc[i][j] = fmaf(a[i], b[j], acc[i][j]);
        }
        __syncthreads();
    }
#pragma unroll
    for (int ig = 0; ig < 2; ++ig) {
#pragma unroll
        for (int ii = 0; ii < 4; ++ii) {
            int i = ig * 4 + ii;
            int grow = row0 + ig * 64 + ty * 4 + ii;
            if (grow >= M) continue;
#pragma unroll
            for (int jg = 0; jg < 2; ++jg) {
                float4 v = make_float4(acc[i][jg * 4 + 0], acc[i][jg * 4 + 1],
                                       acc[i][jg * 4 + 2], acc[i][jg * 4 + 3]);
                if (MODE == 0) {
                    __half* cp = (__half*)C0v + (size_t)grow * 128 + jg * 64 + tx * 4;
                    *(__half2*)(cp + 0) = __floats2half2_rn(v.x, v.y);
                    *(__half2*)(cp + 2) = __floats2half2_rn(v.z, v.w);
                } else {
                    int c = tx * 4;
                    const float* bs = (jg == 0) ? bias0 : bias1;
                    v.x += bs[c + 0];
                    v.y += bs[c + 1];
                    v.z += bs[c + 2];
                    v.w += bs[c + 3];
                    float* cp = ((jg == 0) ? (float*)C0v : C1) + (size_t)grow * 64 + c;
                    *(float4*)cp = v;
                }
            }
        }
    }
}

extern "C" void kernel_launch(void* const* d_in, const int* in_sizes, int n_in,
                              void* d_out, int out_size, void* d_ws, size_t ws_size,
                              hipStream_t stream) {
    const float* x   = (const float*)d_in[0];
    const int*  eidx = (const int*)d_in[1];
    const float* W1  = (const float*)d_in[2];
    const float* b1  = (const float*)d_in[3];
    const float* Wmu = (const float*)d_in[4];
    const float* bmu = (const float*)d_in[5];
    const float* Wls = (const float*)d_in[6];
    const float* bls = (const float*)d_in[7];
    float* out = (float*)d_out;

    const int N = in_sizes[0] / 128;  // 100000
    const int E = in_sizes[1] / 2;    // 1600000
    const int* src = eidx;
    const int* dst = eidx + E;

    int shift = 0;
    while (((N - 1) >> shift) >= NBUCKET) ++shift;  // N=100000 -> 7 (bw=128)
    int chunk = (E + NPB - 1) / NPB;

    char* w = (char*)d_ws;
    size_t off = 0;
    auto alloc = [&](size_t bytes) {
        void* p = w + off;
        off += (bytes + 255) & ~(size_t)255;
        return p;
    };
    // persistent region
    int*       row_ptr      = (int*)alloc((size_t)(N + 1) * 4);
    float*     dinv         = (float*)alloc((size_t)N * 4);
    int*       bucket_total = (int*)alloc(NBUCKET * 4);
    int*       bucket_base  = (int*)alloc(NBUCKET * 4);
    int*       padded_total = (int*)alloc(NBUCKET * 4);
    int*       padded_base  = (int*)alloc(NBUCKET * 4);
    size_t csr_cap = (size_t)E + 31u * (size_t)N + 64;  // pair-padding bound
    long long* csr2         = (long long*)alloc(csr_cap * 8);
    __half*    h1           = (__half*)alloc((size_t)N * 128 * 2);
    // region D: partition-time buffers; then h (fp16) / g (fp16) reuse it.
    // degi persists through bucket_fill (still inside partition lifetime).
    size_t Dstart = off;
    int*       degi     = (int*)alloc((size_t)N * 4);
    int*       blk_hist = (int*)alloc((size_t)NPB * NBUCKET * 4);
    int*       blk_base = (int*)alloc((size_t)NPB * NBUCKET * 4);
    long long* part     = (long long*)alloc((size_t)E * 8);
    size_t Dearly_end = off;
    __half* h = (__half*)(w + Dstart);
    __half* g = (__half*)(w + Dstart);
    size_t Dend = Dstart + (size_t)N * 128 * 2;
    off = (Dearly_end > Dend) ? Dearly_end : Dend;
    if (off > ws_size) return;  // workspace too small: fail cleanly

    // ---- partition + fused CSR build ----
    hist_pass<<<NPB, 256, 0, stream>>>(dst, E, chunk, shift, blk_hist);
    col_scan<<<NBUCKET, 256, 0, stream>>>(blk_hist, blk_base, bucket_total);
    scan_bucket<<<1, 256, 0, stream>>>(bucket_total, bucket_base);
    scatter_pass<<<NPB, 256, 0, stream>>>(src, dst, E, chunk, shift, bucket_base, blk_base, part);
    bucket_count<<<NBUCKET, 256, 0, stream>>>(part, bucket_base, bucket_total, N, shift,
                                              degi, dinv, padded_total);
    scan_bucket<<<1, 256, 0, stream>>>(padded_total, padded_base);
    bucket_fill<<<NBUCKET, 256, 0, stream>>>(part, bucket_base, bucket_total, padded_base,
                                             degi, dinv, N, shift, row_ptr, csr2);

    // ---- compute ----
    // h = x @ W1   (fp16 out)
    sgemm128<0, 0><<<(N + 127) / 128, 256, 0, stream>>>(x, N, W1, nullptr, nullptr, nullptr, h, nullptr);
    // h1 = relu(A @ h + b1)   (fp16 out)
    int gblocks = ((N + 1) / 2 * 64 + 255) / 256;
    gather_pair<1><<<gblocks, 256, 0, stream>>>(h, dinv, row_ptr, csr2, b1, h1, N);
    // g = A @ h1              (fp16 out)
    gather_pair<0><<<gblocks, 256, 0, stream>>>(h1, dinv, row_ptr, csr2, nullptr, g, N);
    // mu | logstd = g @ [W_mu|W_ls] + [b_mu|b_ls]  -> d_out halves (f32)
    sgemm128<1, 1><<<(N + 127) / 128, 256, 0, stream>>>(g, N, Wmu, Wls, bmu, bls, out, out + (size_t)N * 64);
}

// Round 7
// 242.354 us; speedup vs baseline: 2.6187x; 1.2088x over previous
//
#include <hip/hip_runtime.h>
#include <hip/hip_fp16.h>

// ---------------------------------------------------------------------------
// VariationalGCNEncoder on MI355X
//   radix partition by dst -> fused bucket CSR build (padded, pair-equal)
//   wprep: W1^T, [Wmu|Wls]^T -> fp16 [col][K]; bias2 = bmu||bls
//   h  = x @ W1                (MFMA fp16, x converted in-register)
//   h1 = relu(A @ h + b1)      (gather_pair, e-prefetch pipeline, fp16 out)
//   p  = h1 @ [Wmu|Wls]        (MFMA fp16)
//   mu|logstd = A @ p + bias2  (gather_pair, f32 split out)  [re-associated:
//                               (A@h1)@W == A@(h1@W), shared by both heads]
// ---------------------------------------------------------------------------

#define NBUCKET 1024
#define NPB 512  // partition blocks; chunk = ceil(E/NPB)

typedef _Float16 half8_t __attribute__((ext_vector_type(8)));
typedef float f32x4_t __attribute__((ext_vector_type(4)));

// ---- partition pass 1: per-block bucket histogram --------------------------
__global__ __launch_bounds__(256) void hist_pass(const int* __restrict__ dst, int E,
                                                 int chunk, int shift,
                                                 int* __restrict__ blk_hist) {
    __shared__ int hist[NBUCKET];
    for (int i = threadIdx.x; i < NBUCKET; i += 256) hist[i] = 0;
    __syncthreads();
    int b = blockIdx.x;
    int beg = b * chunk;
    int end = beg + chunk; if (end > E) end = E;
    for (int i = beg + threadIdx.x; i < end; i += 256)
        atomicAdd(&hist[dst[i] >> shift], 1);
    __syncthreads();
    for (int i = threadIdx.x; i < NBUCKET; i += 256)
        blk_hist[(size_t)b * NBUCKET + i] = hist[i];
}

// ---- partition pass 2: per-bucket column scan (one block per bucket) -------
__global__ __launch_bounds__(256) void col_scan(const int* __restrict__ blk_hist,
                                                int* __restrict__ blk_base,
                                                int* __restrict__ bucket_total) {
    __shared__ int sh[256];
    int q = blockIdx.x, t = threadIdx.x;
    int v0 = blk_hist[(size_t)(2 * t) * NBUCKET + q];
    int v1 = blk_hist[(size_t)(2 * t + 1) * NBUCKET + q];
    int s = v0 + v1;
    sh[t] = s;
    __syncthreads();
    for (int off = 1; off < 256; off <<= 1) {
        int x = (t >= off) ? sh[t - off] : 0;
        __syncthreads();
        sh[t] += x;
        __syncthreads();
    }
    int pre = sh[t] - s;
    blk_base[(size_t)(2 * t) * NBUCKET + q] = pre;
    blk_base[(size_t)(2 * t + 1) * NBUCKET + q] = pre + v0;
    if (t == 255) bucket_total[q] = sh[255];
}

// ---- exclusive scan of 1024 values (single block), used twice --------------
__global__ __launch_bounds__(256) void scan_bucket(const int* __restrict__ total,
                                                   int* __restrict__ base) {
    __shared__ int sh[256];
    int t = threadIdx.x;
    int idx0 = t * 4;
    int v[4];
#pragma unroll
    for (int k = 0; k < 4; ++k) v[k] = total[idx0 + k];
    int s = v[0] + v[1] + v[2] + v[3];
    sh[t] = s;
    __syncthreads();
    for (int off = 1; off < 256; off <<= 1) {
        int x = (t >= off) ? sh[t - off] : 0;
        __syncthreads();
        sh[t] += x;
        __syncthreads();
    }
    int run = sh[t] - s;
#pragma unroll
    for (int k = 0; k < 4; ++k) {
        base[idx0 + k] = run;
        run += v[k];
    }
}

// ---- partition pass 3: scatter (dst,src) pairs into bucket-ordered part[] --
__global__ __launch_bounds__(256) void scatter_pass(const int* __restrict__ src,
                                                    const int* __restrict__ dst, int E,
                                                    int chunk, int shift,
                                                    const int* __restrict__ bucket_base,
                                                    const int* __restrict__ blk_base,
                                                    long long* __restrict__ part) {
    __shared__ int cur[NBUCKET];
    int b = blockIdx.x;
    for (int i = threadIdx.x; i < NBUCKET; i += 256)
        cur[i] = bucket_base[i] + blk_base[(size_t)b * NBUCKET + i];
    __syncthreads();
    int beg = b * chunk;
    int end = beg + chunk; if (end > E) end = E;
    for (int i = beg + threadIdx.x; i < end; i += 256) {
        int d = dst[i], s = src[i];
        int q = d >> shift;
        int p = atomicAdd(&cur[q], 1);
        part[p] = ((long long)(unsigned)d << 32) | (unsigned)s;
    }
}

// ---- bucket_count: LDS count -> degi, dinv, padded bucket total -------------
__global__ __launch_bounds__(256) void bucket_count(const long long* __restrict__ part,
                                                    const int* __restrict__ bucket_base,
                                                    const int* __restrict__ bucket_total,
                                                    int N, int shift,
                                                    int* __restrict__ degi,
                                                    float* __restrict__ dinv,
                                                    int* __restrict__ padded_total) {
    __shared__ int cnt[128];
    __shared__ int sh[128];
    int b = blockIdx.x, t = threadIdx.x;
    if (t < 128) cnt[t] = 0;
    __syncthreads();
    int node0 = b << shift;
    int beg = bucket_base[b];
    int end = beg + bucket_total[b];
    for (int i = beg + t; i < end; i += 256) {
        int d = (int)((unsigned long long)part[i] >> 32);
        atomicAdd(&cnt[d - node0], 1);
    }
    __syncthreads();
    if (t < 128) {
        int node = node0 + t;
        int c = (node < N) ? cnt[t] : 0;
        if (node < N) {
            degi[node] = c;
            dinv[node] = rsqrtf((float)(c + 1));
        }
        sh[t] = c;
    }
    __syncthreads();
    int padded = 0;
    if (t < 128) {
        int node = node0 + t;
        if (node < N) {
            int mine = (sh[t] + 15) >> 4;
            int pi = t ^ 1;
            int pnode = node0 + pi;
            int theirs = (pnode < N) ? ((sh[pi] + 15) >> 4) : 0;
            int L = mine > theirs ? mine : theirs;
            padded = L << 4;
        }
    }
    __syncthreads();
    if (t < 128) sh[t] = padded;
    __syncthreads();
    for (int off = 64; off >= 1; off >>= 1) {
        if (t < off) sh[t] += sh[t + off];
        __syncthreads();
    }
    if (t == 0) padded_total[b] = sh[0];
}

// ---- bucket_fill: row_ptr + weighted scatter into padded csr2 ---------------
__global__ __launch_bounds__(256) void bucket_fill(const long long* __restrict__ part,
                                                   const int* __restrict__ bucket_base,
                                                   const int* __restrict__ bucket_total,
                                                   const int* __restrict__ padded_base,
                                                   const int* __restrict__ degi,
                                                   const float* __restrict__ dinv,
                                                   int N, int shift,
                                                   int* __restrict__ row_ptr,
                                                   long long* __restrict__ csr2) {
    __shared__ int sh[128];
    __shared__ int pexcl[128];
    __shared__ int padarr[128];
    __shared__ int cur[128];
    __shared__ float dvl[128];
    int b = blockIdx.x, t = threadIdx.x;
    int node0 = b << shift;
    int pbase = padded_base[b];

    if (t < 128) {
        int node = node0 + t;
        int deg = (node < N) ? degi[node] : 0;
        dvl[t] = (node < N) ? dinv[node] : 0.0f;
        sh[t] = deg;
    }
    __syncthreads();
    int padded = 0;
    if (t < 128) {
        int node = node0 + t;
        if (node < N) {
            int mine = (sh[t] + 15) >> 4;
            int pi = t ^ 1;
            int pnode = node0 + pi;
            int theirs = (pnode < N) ? ((sh[pi] + 15) >> 4) : 0;
            int L = mine > theirs ? mine : theirs;
            padded = L << 4;
        }
        padarr[t] = padded;
    }
    __syncthreads();
    if (t < 128) sh[t] = padded;
    __syncthreads();
    for (int off = 1; off < 128; off <<= 1) {
        int x = 0;
        if (t < 128 && t >= off) x = sh[t - off];
        __syncthreads();
        if (t < 128) sh[t] += x;
        __syncthreads();
    }
    if (t < 128) {
        int excl = sh[t] - padarr[t];
        pexcl[t] = excl;
        cur[t] = pbase + excl;
        int node = node0 + t;
        if (node < N) row_ptr[node] = pbase + excl;
    }
    __syncthreads();
    if (t == 0) {
        int boundary = node0 + 128;
        if (boundary > N) boundary = N;
        row_ptr[boundary] = pbase + sh[127];  // benign overlap with next bucket
    }
    int ebeg = bucket_base[b];
    int eend = ebeg + bucket_total[b];
    for (int i = ebeg + t; i < eend; i += 256) {
        long long pr = part[i];
        int d = (int)((unsigned long long)pr >> 32);
        int s = (int)(unsigned)(pr & 0xffffffffLL);
        int dl = d - node0;
        int p = atomicAdd(&cur[dl], 1);
        float w = dinv[s] * dvl[dl];
        csr2[p] = (long long)(unsigned)s |
                  ((long long)(unsigned)__float_as_uint(w) << 32);
    }
    __syncthreads();
    if (t < 128) {
        int node = node0 + t;
        if (node < N) {
            int endp = pbase + pexcl[t] + padarr[t];
            long long rec = (long long)(unsigned)node;  // hi=0 -> w=0.0f
            for (int p = cur[t]; p < endp; ++p) csr2[p] = rec;
        }
    }
}

// ---- wprep: weights -> fp16 [out-col][K], bias2 = bmu||bls ------------------
__global__ __launch_bounds__(256) void wprep(const float* __restrict__ W1,
                                             const float* __restrict__ Wmu,
                                             const float* __restrict__ bmu,
                                             const float* __restrict__ Wls,
                                             const float* __restrict__ bls,
                                             __half* __restrict__ Wt1,
                                             __half* __restrict__ Wt2,
                                             float* __restrict__ bias2) {
    int i = blockIdx.x * 256 + threadIdx.x;
    if (i < 16384) {
        int n = i >> 7, k = i & 127;
        Wt1[i] = __float2half_rn(W1[k * 128 + n]);
        float v = (n < 64) ? Wmu[k * 64 + n] : Wls[k * 64 + (n - 64)];
        Wt2[i] = __float2half_rn(v);
    }
    if (i < 64) {
        bias2[i] = bmu[i];
        bias2[64 + i] = bls[i];
    }
}

// ---- MFMA GEMM: C[M,128](fp16) = A[M,128] @ Bt^T ---------------------------
// Bt fp16 [128][128]: row = out-col, K contiguous. 256 thr, 4 waves x 32 rows.
// mfma_f32_16x16x32_f16: A-frag lane: row=l&15, k=(l>>4)*8+i (16B contig);
// B-frag: col=l&15, same k slice; C: col=l&15, row=(l>>4)*4+reg.
template <int AF32>
__global__ __launch_bounds__(256) void gemm_mfma(const void* __restrict__ Av, int M,
                                                 const __half* __restrict__ Bt,
                                                 __half* __restrict__ C) {
    __shared__ __half Bs[128][136];  // rows 272B (16-aligned), pad vs conflicts
    int tid = threadIdx.x;
#pragma unroll
    for (int i = 0; i < 8; ++i) {
        int idx = tid + i * 256;       // 0..2047, 8 halves each
        int r = idx >> 4;
        int c8 = (idx & 15) << 3;
        *(float4*)&Bs[r][c8] = *(const float4*)(Bt + r * 128 + c8);
    }
    __syncthreads();
    int wave = tid >> 6, lane = tid & 63;
    int lr = lane & 15, lk = lane >> 4;
    int row0 = blockIdx.x * 128 + wave * 32;

    f32x4_t acc[2][8];
#pragma unroll
    for (int rt = 0; rt < 2; ++rt)
#pragma unroll
        for (int ct = 0; ct < 8; ++ct) acc[rt][ct] = (f32x4_t)0.0f;

    half8_t afr[2][4];
#pragma unroll
    for (int rt = 0; rt < 2; ++rt) {
        int row = row0 + rt * 16 + lr;
        if (row >= M) row = M - 1;
        if (AF32) {
            const float* A = (const float*)Av + (size_t)row * 128;
#pragma unroll
            for (int ks = 0; ks < 4; ++ks) {
                float4 v0 = *(const float4*)(A + ks * 32 + lk * 8);
                float4 v1 = *(const float4*)(A + ks * 32 + lk * 8 + 4);
                half8_t f;
                f[0] = (_Float16)v0.x; f[1] = (_Float16)v0.y;
                f[2] = (_Float16)v0.z; f[3] = (_Float16)v0.w;
                f[4] = (_Float16)v1.x; f[5] = (_Float16)v1.y;
                f[6] = (_Float16)v1.z; f[7] = (_Float16)v1.w;
                afr[rt][ks] = f;
            }
        } else {
            const __half* A = (const __half*)Av + (size_t)row * 128;
#pragma unroll
            for (int ks = 0; ks < 4; ++ks)
                afr[rt][ks] = *(const half8_t*)(A + ks * 32 + lk * 8);
        }
    }
#pragma unroll
    for (int ks = 0; ks < 4; ++ks)
#pragma unroll
        for (int ct = 0; ct < 8; ++ct) {
            half8_t b = *(const half8_t*)&Bs[ct * 16 + lr][ks * 32 + lk * 8];
            acc[0][ct] = __builtin_amdgcn_mfma_f32_16x16x32_f16(afr[0][ks], b, acc[0][ct], 0, 0, 0);
            acc[1][ct] = __builtin_amdgcn_mfma_f32_16x16x32_f16(afr[1][ks], b, acc[1][ct], 0, 0, 0);
        }
#pragma unroll
    for (int rt = 0; rt < 2; ++rt)
#pragma unroll
        for (int r = 0; r < 4; ++r) {
            int row = row0 + rt * 16 + lk * 4 + r;
            if (row < M) {
#pragma unroll
                for (int ct = 0; ct < 8; ++ct)
                    C[(size_t)row * 128 + ct * 16 + lr] = __float2half_rn(acc[rt][ct][r]);
            }
        }
}

// ---- gather: 2 nodes/wave, padded mask-free loop, e-prefetch pipeline -------
// MODE 0: out = relu(acc + bias) -> fp16 [n][128]
// MODE 1: out = acc + bias       -> f32 mu [n][64] || logstd [n][64]
template <int MODE>
__global__ __launch_bounds__(256) void gather_pair(const __half* __restrict__ h,
                                                   const float* __restrict__ dinv,
                                                   const int* __restrict__ row_ptr,
                                                   const long long* __restrict__ csr2,
                                                   const float* __restrict__ bias,
                                                   void* __restrict__ outv, int n) {
    int wv = (blockIdx.x * 256 + threadIdx.x) >> 6;
    int lane = threadIdx.x & 63;
    int nodeA = wv * 2;
    if (nodeA >= n) return;
    int half = lane >> 5;
    int grp2 = (lane >> 4) & 1;
    int cs = lane & 15;
    int bvalid = (nodeA + 1) < n;
    int wid = nodeA + (half & bvalid);
    float dv = dinv[wid];
    int beg = row_ptr[wid];
    int end = row_ptr[wid + 1];

    float acc[8];
    {
        float4 raw = *(const float4*)(h + (size_t)wid * 128 + cs * 8);
        const __half2* hp = (const __half2*)&raw;
        float sw = (grp2 == 0) ? dv * dv : 0.0f;
#pragma unroll
        for (int q = 0; q < 4; ++q) {
            float2 f = __half22float2(hp[q]);
            acc[2 * q]     = sw * f.x;
            acc[2 * q + 1] = sw * f.y;
        }
    }

    long long e[8];
    if (beg < end) {
#pragma unroll
        for (int u = 0; u < 8; ++u) e[u] = csr2[beg + u * 2 + grp2];
    }
#pragma unroll 1
    for (int j = beg; j < end; j += 16) {
        int jn = j + 16;
        int jp = (jn < end) ? jn : beg;
        long long en[8];
#pragma unroll
        for (int u = 0; u < 8; ++u) en[u] = csr2[jp + u * 2 + grp2];
        float4 raw[8];
        float wgt[8];
#pragma unroll
        for (int u = 0; u < 8; ++u) {
            int s = (int)(unsigned)(e[u] & 0xffffffffLL);
            wgt[u] = __uint_as_float((unsigned)((unsigned long long)e[u] >> 32));
            raw[u] = *(const float4*)(h + (size_t)s * 128 + cs * 8);
        }
#pragma unroll
        for (int u = 0; u < 8; ++u) {
            const __half2* hp = (const __half2*)&raw[u];
#pragma unroll
            for (int q = 0; q < 4; ++q) {
                float2 f = __half22float2(hp[q]);
                acc[2 * q]     = fmaf(wgt[u], f.x, acc[2 * q]);
                acc[2 * q + 1] = fmaf(wgt[u], f.y, acc[2 * q + 1]);
            }
        }
#pragma unroll
        for (int u = 0; u < 8; ++u) e[u] = en[u];
    }

#pragma unroll
    for (int q = 0; q < 8; ++q) acc[q] += __shfl_xor(acc[q], 16, 64);

    {
        const float4* bp = (const float4*)(bias + cs * 8);
        float4 b0 = bp[0], b1 = bp[1];
        if (MODE == 0) {
            acc[0] = fmaxf(acc[0] + b0.x, 0.0f);
            acc[1] = fmaxf(acc[1] + b0.y, 0.0f);
            acc[2] = fmaxf(acc[2] + b0.z, 0.0f);
            acc[3] = fmaxf(acc[3] + b0.w, 0.0f);
            acc[4] = fmaxf(acc[4] + b1.x, 0.0f);
            acc[5] = fmaxf(acc[5] + b1.y, 0.0f);
            acc[6] = fmaxf(acc[6] + b1.z, 0.0f);
            acc[7] = fmaxf(acc[7] + b1.w, 0.0f);
        } else {
            acc[0] += b0.x; acc[1] += b0.y; acc[2] += b0.z; acc[3] += b0.w;
            acc[4] += b1.x; acc[5] += b1.y; acc[6] += b1.z; acc[7] += b1.w;
        }
    }

    if ((lane & 31) < 16 && (half == 0 || bvalid)) {
        if (MODE == 0) {
            union { __half2 h2[4]; float4 f4; } u;
            u.h2[0] = __floats2half2_rn(acc[0], acc[1]);
            u.h2[1] = __floats2half2_rn(acc[2], acc[3]);
            u.h2[2] = __floats2half2_rn(acc[4], acc[5]);
            u.h2[3] = __floats2half2_rn(acc[6], acc[7]);
            *(float4*)((__half*)outv + (size_t)wid * 128 + cs * 8) = u.f4;
        } else {
            float* mu = (float*)outv;
            float* ls = mu + (size_t)n * 64;
            float* op = (cs < 8) ? (mu + (size_t)wid * 64 + cs * 8)
                                 : (ls + (size_t)wid * 64 + (cs - 8) * 8);
            ((float4*)op)[0] = make_float4(acc[0], acc[1], acc[2], acc[3]);
            ((float4*)op)[1] = make_float4(acc[4], acc[5], acc[6], acc[7]);
        }
    }
}

extern "C" void kernel_launch(void* const* d_in, const int* in_sizes, int n_in,
                              void* d_out, int out_size, void* d_ws, size_t ws_size,
                              hipStream_t stream) {
    const float* x   = (const float*)d_in[0];
    const int*  eidx = (const int*)d_in[1];
    const float* W1  = (const float*)d_in[2];
    const float* b1  = (const float*)d_in[3];
    const float* Wmu = (const float*)d_in[4];
    const float* bmu = (const float*)d_in[5];
    const float* Wls = (const float*)d_in[6];
    const float* bls = (const float*)d_in[7];
    float* out = (float*)d_out;

    const int N = in_sizes[0] / 128;  // 100000
    const int E = in_sizes[1] / 2;    // 1600000
    const int* src = eidx;
    const int* dst = eidx + E;

    int shift = 0;
    while (((N - 1) >> shift) >= NBUCKET) ++shift;  // N=100000 -> 7 (bw=128)
    int chunk = (E + NPB - 1) / NPB;

    char* w = (char*)d_ws;
    size_t off = 0;
    auto alloc = [&](size_t bytes) {
        void* p = w + off;
        off += (bytes + 255) & ~(size_t)255;
        return p;
    };
    // persistent region
    int*       row_ptr      = (int*)alloc((size_t)(N + 1) * 4);
    float*     dinv         = (float*)alloc((size_t)N * 4);
    int*       bucket_total = (int*)alloc(NBUCKET * 4);
    int*       bucket_base  = (int*)alloc(NBUCKET * 4);
    int*       padded_total = (int*)alloc(NBUCKET * 4);
    int*       padded_base  = (int*)alloc(NBUCKET * 4);
    __half*    Wt1          = (__half*)alloc(16384 * 2);
    __half*    Wt2          = (__half*)alloc(16384 * 2);
    float*     bias2        = (float*)alloc(128 * 4);
    size_t csr_cap = (size_t)E + 31u * (size_t)N + 64;  // pair-padding bound
    long long* csr2         = (long long*)alloc(csr_cap * 8);
    __half*    h1           = (__half*)alloc((size_t)N * 128 * 2);
    // region D: partition buffers; then h (fp16), then p (fp16) reuse it
    size_t Dstart = off;
    int*       degi     = (int*)alloc((size_t)N * 4);
    int*       blk_hist = (int*)alloc((size_t)NPB * NBUCKET * 4);
    int*       blk_base = (int*)alloc((size_t)NPB * NBUCKET * 4);
    long long* part     = (long long*)alloc((size_t)E * 8);
    size_t Dearly_end = off;
    __half* h = (__half*)(w + Dstart);
    __half* p = (__half*)(w + Dstart);
    size_t Dend = Dstart + (size_t)N * 128 * 2;
    off = (Dearly_end > Dend) ? Dearly_end : Dend;
    if (off > ws_size) return;  // workspace too small: fail cleanly

    // ---- weight prep + partition + fused CSR build ----
    wprep<<<64, 256, 0, stream>>>(W1, Wmu, bmu, Wls, bls, Wt1, Wt2, bias2);
    hist_pass<<<NPB, 256, 0, stream>>>(dst, E, chunk, shift, blk_hist);
    col_scan<<<NBUCKET, 256, 0, stream>>>(blk_hist, blk_base, bucket_total);
    scan_bucket<<<1, 256, 0, stream>>>(bucket_total, bucket_base);
    scatter_pass<<<NPB, 256, 0, stream>>>(src, dst, E, chunk, shift, bucket_base, blk_base, part);
    bucket_count<<<NBUCKET, 256, 0, stream>>>(part, bucket_base, bucket_total, N, shift,
                                              degi, dinv, padded_total);
    scan_bucket<<<1, 256, 0, stream>>>(padded_total, padded_base);
    bucket_fill<<<NBUCKET, 256, 0, stream>>>(part, bucket_base, bucket_total, padded_base,
                                             degi, dinv, N, shift, row_ptr, csr2);

    // ---- compute ----
    int gemm_blocks = (N + 127) / 128;
    int gblocks = (((N + 1) / 2) * 64 + 255) / 256;
    // h = x @ W1  (fp16)
    gemm_mfma<1><<<gemm_blocks, 256, 0, stream>>>(x, N, Wt1, h);
    // h1 = relu(A @ h + b1)  (fp16)
    gather_pair<0><<<gblocks, 256, 0, stream>>>(h, dinv, row_ptr, csr2, b1, h1, N);
    // p = h1 @ [Wmu|Wls]  (fp16)
    gemm_mfma<0><<<gemm_blocks, 256, 0, stream>>>(h1, N, Wt2, p);
    // mu|logstd = A @ p + bias2  -> d_out (f32 halves)
    gather_pair<1><<<gblocks, 256, 0, stream>>>(p, dinv, row_ptr, csr2, bias2, out, N);
}